// Round 2
// baseline (446.833 us; speedup 1.0000x reference)
//
#include <hip/hip_runtime.h>
#include <hip/hip_bf16.h>

// GCN 2-layer: out = log_softmax(GCN2(relu(GCN1(x))))
// Round 9: fix R8's spill regression. gfx950 unified VGPR+AGPR file means
// R7's gemm1 used 52 VGPR + 32 AGPR = 84 regs/wave -> stuck in the
// 4-waves/SIMD occupancy band; R8's (1024,8) cap of 64 forced spills
// (+29MB scratch traffic, WRITE 25->47MB). R9 genuinely shrinks the live
// set instead: gemm1 is N-split via blockIdx.y (64-col halves), so
// acc[4]=16 AGPR + ~35 VGPR fits the 64-reg band -> 8 waves/SIMD legal,
// and the W-half LDS table is 32KB -> 4 blocks/CU. Both constraints now
// allow 32 waves/CU. x is load-issued twice (once per half) but the
// second pass hits L3.
// gemm2 reverted to R7 (512,4) -- its ~66 regs would spill under a 64 cap.
// Aggs keep the x2 gather unroll (measured neutral). Sort pipeline
// unchanged.

#define N_NODES 100000
#define F_IN 256
#define F_MID 128
#define F_OUT 64

#define BSHIFT 8                      // 256 nodes per bucket
#define BNODES 256
#define NBUCKETS ((N_NODES + BNODES - 1) / BNODES)   // 391
#define BCAP 6144                     // mean 4096, sigma ~64 -> +32 sigma
#define EPB 4096                      // edges per scatter block

typedef __attribute__((ext_vector_type(8))) short short8;
typedef __attribute__((ext_vector_type(4))) float f32x4;

__device__ inline ushort bf16_rne(float f) {
    uint u = __float_as_uint(f);
    u += 0x7FFF + ((u >> 16) & 1);
    return (ushort)(u >> 16);
}
__device__ inline float lo16(uint r) { return __uint_as_float(r << 16); }
__device__ inline float hi16(uint r) { return __uint_as_float(r & 0xffff0000u); }
__device__ inline uint pack_bf2(float a, float b) {
    return (uint)bf16_rne(a) | ((uint)bf16_rne(b) << 16);
}

// ---------------- two-level bucket sort ----------------

// S1: block-binned scatter. packed = (dst&255)<<17 | src  (25 bits)
__global__ __launch_bounds__(256)
void bucket_scatter_kernel(const int* __restrict__ src, const int* __restrict__ dst,
                           int* __restrict__ bcur, uint* __restrict__ ebuf, int E) {
    __shared__ int curL[NBUCKETS];
    int t = threadIdx.x;
    int e0 = blockIdx.x * EPB;
    int e1 = e0 + EPB; if (e1 > E) e1 = E;

    for (int i = t; i < NBUCKETS; i += 256) curL[i] = 0;
    __syncthreads();
    for (int i = e0 + t; i < e1; i += 256) atomicAdd(&curL[dst[i] >> BSHIFT], 1);
    __syncthreads();
    for (int i = t; i < NBUCKETS; i += 256) {
        int h = curL[i];
        curL[i] = h ? atomicAdd(&bcur[i], h) : 0;
    }
    __syncthreads();
    for (int i = e0 + t; i < e1; i += 256) {
        int d = dst[i], s = src[i];
        int b = d >> BSHIFT;
        int pos = atomicAdd(&curL[b], 1);
        if (pos < BCAP) ebuf[(size_t)b * BCAP + pos] = ((uint)(d & (BNODES - 1)) << 17) | (uint)s;
    }
}

// S2: per-bucket counting sort; emits ssrc + rs + cnt + dinv.
__global__ __launch_bounds__(256)
void bucket_sort_kernel(const uint* __restrict__ ebuf, const int* __restrict__ bcur,
                        int* __restrict__ ssrc, int* __restrict__ rs, int* __restrict__ cnt,
                        float* __restrict__ dinv, int n) {
    __shared__ uint eL[BCAP];          // 24 KB
    __shared__ int hist[BNODES], ps[BNODES];
    int b = blockIdx.x, t = threadIdx.x;
    int nb = bcur[b];
    if (nb > BCAP) nb = BCAP;
    for (int i = t; i < nb; i += 256) eL[i] = ebuf[(size_t)b * BCAP + i];
    hist[t] = 0;
    __syncthreads();
    for (int i = t; i < nb; i += 256) atomicAdd(&hist[eL[i] >> 17], 1);
    __syncthreads();
    ps[t] = hist[t];
    __syncthreads();
#pragma unroll
    for (int off = 1; off < BNODES; off <<= 1) {
        int v = (t >= off) ? ps[t - off] : 0;
        __syncthreads();
        ps[t] += v;
        __syncthreads();
    }
    int excl = ps[t] - hist[t];
    int node = b * BNODES + t;
    if (node < n) {
        rs[node] = b * BCAP + excl;
        cnt[node] = hist[t];
        dinv[node] = 1.0f / sqrtf((float)hist[t] + 1.0f);
    }
    __syncthreads();
    ps[t] = excl;                      // reuse as running cursor
    __syncthreads();
    for (int i = t; i < nb; i += 256) {
        uint e = eL[i];
        int d = e >> 17;
        int p = atomicAdd(&ps[d], 1);
        ssrc[(size_t)b * BCAP + p] = (int)(e & 0x1FFFF);
    }
}

// ---------------- weight prep: fragment-ordered bf16 ----------------
// mfma_f32_16x16x32_bf16 B-frag: lane holds B[k=(lane>>4)*8+j][n=lane&15].
__global__ __launch_bounds__(256)
void wprep_kernel(const float* __restrict__ W1, const float* __restrict__ W2,
                  short8* __restrict__ W1f, short8* __restrict__ W2f) {
    int b = blockIdx.x;
    if (b < 16) {
        int f = b * 256 + threadIdx.x;
        int k0 = f >> 9, nt = (f >> 6) & 7, ln = f & 63;
        int kbase = k0 * 32 + (ln >> 4) * 8;
        int n = nt * 16 + (ln & 15);
        short8 fr;
#pragma unroll
        for (int j = 0; j < 8; ++j) fr[j] = (short)bf16_rne(W1[(kbase + j) * F_MID + n]);
        W1f[f] = fr;
    } else {
        int f = (b - 16) * 256 + threadIdx.x;
        int k0 = f >> 8, nt = (f >> 6) & 3, ln = f & 63;
        int kbase = k0 * 32 + (ln >> 4) * 8;
        int n = nt * 16 + (ln & 15);
        short8 fr;
#pragma unroll
        for (int j = 0; j < 8; ++j) fr[j] = (short)bf16_rne(W2[(kbase + j) * F_OUT + n]);
        W2f[f] = fr;
    }
}

// ---------------- MFMA GEMMs ----------------
// A: lane holds A[m=lane&15][k=(lane>>4)*8+j]; C/D: col=lane&15, row=(lane>>4)*4+reg.

// h1s[M,128](bf16) = dinv[m] * (x[M,256](fp32) @ W1bf16)
// 2D grid: blockIdx.y = 64-col half. 8 waves x 16 rows = 128-row tile.
// acc[4] = 16 AGPR; total regs ~50 -> 8 waves/SIMD band; LDS 32KB -> 4
// blocks/CU. Occupancy cap 32 waves/CU.
__global__ __launch_bounds__(512, 8)
void gemm1_kernel(const float* __restrict__ A, const short8* __restrict__ Wf,
                  const float* __restrict__ dinv, ushort* __restrict__ C,
                  int M) {
    __shared__ short8 BsF[2048];   // 32 KB: [k0][ntl][lane], ntl in 0..3
    int tid = threadIdx.x;
    int lane = tid & 63, w = tid >> 6;        // w in 0..7
    int nh = blockIdx.y;                      // col-half 0/1
    for (int i = tid; i < 2048; i += 512) {
        int k0 = i >> 8, ntl = (i >> 6) & 3, ln = i & 63;
        BsF[i] = Wf[(k0 * 8 + nh * 4 + ntl) * 64 + ln];
    }
    __syncthreads();

    const float4 z4 = make_float4(0.f, 0.f, 0.f, 0.f);
    int m0 = blockIdx.x * 128 + w * 16;
    int m = m0 + (lane & 15);
    bool mOk = (m < M);
    const float4* aptr = (const float4*)&A[(size_t)(mOk ? m : 0) * F_IN + (lane >> 4) * 8];

    f32x4 acc[4];
#pragma unroll
    for (int nt = 0; nt < 4; ++nt) acc[nt] = (f32x4){0.f, 0.f, 0.f, 0.f};

    float4 v0 = mOk ? aptr[0] : z4;
    float4 v1 = mOk ? aptr[1] : z4;

#pragma unroll
    for (int k0 = 0; k0 < 8; ++k0) {
        short8 af;
        af[0] = (short)bf16_rne(v0.x); af[1] = (short)bf16_rne(v0.y);
        af[2] = (short)bf16_rne(v0.z); af[3] = (short)bf16_rne(v0.w);
        af[4] = (short)bf16_rne(v1.x); af[5] = (short)bf16_rne(v1.y);
        af[6] = (short)bf16_rne(v1.z); af[7] = (short)bf16_rne(v1.w);
        if (k0 < 7) {   // 1-deep prefetch of next K-step
            v0 = mOk ? aptr[(k0 + 1) * 8 + 0] : z4;
            v1 = mOk ? aptr[(k0 + 1) * 8 + 1] : z4;
        }
#pragma unroll
        for (int nt = 0; nt < 4; ++nt) {
            short8 bfr = BsF[(k0 * 4 + nt) * 64 + lane];
            acc[nt] = __builtin_amdgcn_mfma_f32_16x16x32_bf16(af, bfr, acc[nt], 0, 0, 0);
        }
    }
#pragma unroll
    for (int i = 0; i < 4; ++i) {
        int r = m0 + (lane >> 4) * 4 + i;
        if (r < M) {
            float dv = dinv[r];
#pragma unroll
            for (int nt = 0; nt < 4; ++nt)
                C[(size_t)r * F_MID + (nh * 4 + nt) * 16 + (lane & 15)] = bf16_rne(dv * acc[nt][i]);
        }
    }
}

// h2s[M,64](bf16) = dinv[m] * (h1a[M,128](bf16) @ W2bf16)
__global__ __launch_bounds__(512, 4)
void gemm2_kernel(const ushort* __restrict__ A, const short8* __restrict__ Wf,
                  const float* __restrict__ dinv, ushort* __restrict__ C,
                  int M) {
    __shared__ short8 BsF[1024];   // 16 KB
    int tid = threadIdx.x;
    int lane = tid & 63, w = tid >> 6;
    for (int f = tid; f < 1024; f += 512) BsF[f] = Wf[f];
    __syncthreads();

    int m0 = blockIdx.x * 128 + w * 16;
    int m = m0 + (lane & 15);
    bool mOk = (m < M);

    f32x4 acc[4];
#pragma unroll
    for (int nt = 0; nt < 4; ++nt) acc[nt] = (f32x4){0.f, 0.f, 0.f, 0.f};

    short8 afr[4];
#pragma unroll
    for (int k0 = 0; k0 < 4; ++k0) {
        short8 af = (short8){0, 0, 0, 0, 0, 0, 0, 0};
        if (mOk) af = *(const short8*)&A[(size_t)m * F_MID + k0 * 32 + (lane >> 4) * 8];
        afr[k0] = af;
    }
#pragma unroll
    for (int k0 = 0; k0 < 4; ++k0)
#pragma unroll
        for (int nt = 0; nt < 4; ++nt) {
            short8 bfr = BsF[(k0 * 4 + nt) * 64 + lane];
            acc[nt] = __builtin_amdgcn_mfma_f32_16x16x32_bf16(afr[k0], bfr, acc[nt], 0, 0, 0);
        }
#pragma unroll
    for (int i = 0; i < 4; ++i) {
        int r = m0 + (lane >> 4) * 4 + i;
        if (r < M) {
            float dv = dinv[r];
#pragma unroll
            for (int nt = 0; nt < 4; ++nt)
                C[(size_t)r * F_OUT + nt * 16 + (lane & 15)] = bf16_rne(dv * acc[nt][i]);
        }
    }
}

// ---------------- aggregation ----------------
// agg1: rows pre-scaled by dinv[src]. One wave/node; quarter q handles edge
// base+q and base+4+q (x2 unroll -> 8 gathers in flight); 16 lanes x uint4
// (16B) cover the 256-B row; butterfly fold at end.
__global__ __launch_bounds__(256)
void agg1_kernel(const uint4* __restrict__ h, const int* __restrict__ rs,
                 const int* __restrict__ cnt, const int* __restrict__ ssrc,
                 const float* __restrict__ dinv, const float* __restrict__ bias,
                 uint4* __restrict__ outp, int n) {
    int w = threadIdx.x >> 6, lane = threadIdx.x & 63;
    int node = blockIdx.x * 4 + w;
    if (node >= n) return;
    int q = lane >> 4, c16 = lane & 15;
    int start = rs[node], c = cnt[node];
    float dn = dinv[node];
    float a[8];
#pragma unroll
    for (int i = 0; i < 8; ++i) a[i] = 0.f;

    for (int base = 0; base < c; base += 8) {
        int e0 = base + q, e1 = base + 4 + q;
        bool p0 = e0 < c, p1 = e1 < c;
        uint4 r0, r1;
        int s0 = 0, s1 = 0;
        if (p0) s0 = ssrc[start + e0];
        if (p1) s1 = ssrc[start + e1];
        if (p0) r0 = h[(size_t)s0 * 16 + c16];
        if (p1) r1 = h[(size_t)s1 * 16 + c16];
        if (p0) {
            a[0] += lo16(r0.x); a[1] += hi16(r0.x);
            a[2] += lo16(r0.y); a[3] += hi16(r0.y);
            a[4] += lo16(r0.z); a[5] += hi16(r0.z);
            a[6] += lo16(r0.w); a[7] += hi16(r0.w);
        }
        if (p1) {
            a[0] += lo16(r1.x); a[1] += hi16(r1.x);
            a[2] += lo16(r1.y); a[3] += hi16(r1.y);
            a[4] += lo16(r1.z); a[5] += hi16(r1.z);
            a[6] += lo16(r1.w); a[7] += hi16(r1.w);
        }
    }
#pragma unroll
    for (int i = 0; i < 8; ++i) {
        a[i] += __shfl_xor(a[i], 16);
        a[i] += __shfl_xor(a[i], 32);
    }
    uint4 sr = h[(size_t)node * 16 + c16];
    const float4* b4 = (const float4*)bias;
    float4 b0 = b4[c16 * 2], b1 = b4[c16 * 2 + 1];
    float o0 = fmaxf(fmaf(dn, a[0] + lo16(sr.x), b0.x), 0.f);
    float o1 = fmaxf(fmaf(dn, a[1] + hi16(sr.x), b0.y), 0.f);
    float o2 = fmaxf(fmaf(dn, a[2] + lo16(sr.y), b0.z), 0.f);
    float o3 = fmaxf(fmaf(dn, a[3] + hi16(sr.y), b0.w), 0.f);
    float o4 = fmaxf(fmaf(dn, a[4] + lo16(sr.z), b1.x), 0.f);
    float o5 = fmaxf(fmaf(dn, a[5] + hi16(sr.z), b1.y), 0.f);
    float o6 = fmaxf(fmaf(dn, a[6] + lo16(sr.w), b1.z), 0.f);
    float o7 = fmaxf(fmaf(dn, a[7] + hi16(sr.w), b1.w), 0.f);
    if (q == 0) {
        uint4 ov;
        ov.x = pack_bf2(o0, o1);
        ov.y = pack_bf2(o2, o3);
        ov.z = pack_bf2(o4, o5);
        ov.w = pack_bf2(o6, o7);
        outp[(size_t)node * 16 + c16] = ov;
    }
}

// agg2: 64-col bf16 rows (128 B), 16 lanes x uint2; x2-unrolled gather;
// fused bias + log_softmax.
__global__ __launch_bounds__(256)
void agg2_kernel(const uint2* __restrict__ h, const int* __restrict__ rs,
                 const int* __restrict__ cnt, const int* __restrict__ ssrc,
                 const float* __restrict__ dinv, const float* __restrict__ bias,
                 float4* __restrict__ out4, int n) {
    int w = threadIdx.x >> 6, lane = threadIdx.x & 63;
    int node = blockIdx.x * 4 + w;
    if (node >= n) return;
    int q = lane >> 4, c16 = lane & 15;
    int start = rs[node], c = cnt[node];
    float dn = dinv[node];
    float a[4];
#pragma unroll
    for (int i = 0; i < 4; ++i) a[i] = 0.f;

    for (int base = 0; base < c; base += 8) {
        int e0 = base + q, e1 = base + 4 + q;
        bool p0 = e0 < c, p1 = e1 < c;
        uint2 r0, r1;
        int s0 = 0, s1 = 0;
        if (p0) s0 = ssrc[start + e0];
        if (p1) s1 = ssrc[start + e1];
        if (p0) r0 = h[(size_t)s0 * 16 + c16];
        if (p1) r1 = h[(size_t)s1 * 16 + c16];
        if (p0) {
            a[0] += lo16(r0.x); a[1] += hi16(r0.x);
            a[2] += lo16(r0.y); a[3] += hi16(r0.y);
        }
        if (p1) {
            a[0] += lo16(r1.x); a[1] += hi16(r1.x);
            a[2] += lo16(r1.y); a[3] += hi16(r1.y);
        }
    }
#pragma unroll
    for (int i = 0; i < 4; ++i) {
        a[i] += __shfl_xor(a[i], 16);
        a[i] += __shfl_xor(a[i], 32);
    }
    uint2 sr = h[(size_t)node * 16 + c16];
    float4 bv = ((const float4*)bias)[c16];
    float v0 = fmaf(dn, a[0] + lo16(sr.x), bv.x);
    float v1 = fmaf(dn, a[1] + hi16(sr.x), bv.y);
    float v2 = fmaf(dn, a[2] + lo16(sr.y), bv.z);
    float v3 = fmaf(dn, a[3] + hi16(sr.y), bv.w);
    float m = fmaxf(fmaxf(v0, v1), fmaxf(v2, v3));
#pragma unroll
    for (int off = 1; off < 16; off <<= 1) m = fmaxf(m, __shfl_xor(m, off));
    float ssum = expf(v0 - m) + expf(v1 - m) + expf(v2 - m) + expf(v3 - m);
#pragma unroll
    for (int off = 1; off < 16; off <<= 1) ssum += __shfl_xor(ssum, off);
    float lg = m + logf(ssum);
    if (q == 0) out4[(size_t)node * 16 + c16] = make_float4(v0 - lg, v1 - lg, v2 - lg, v3 - lg);
}

// ---------------- launch ----------------

extern "C" void kernel_launch(void* const* d_in, const int* in_sizes, int n_in,
                              void* d_out, int out_size, void* d_ws, size_t ws_size,
                              hipStream_t stream) {
    const float* x  = (const float*)d_in[0];
    const int*   ei = (const int*)d_in[1];
    const float* W1 = (const float*)d_in[2];
    const float* b1 = (const float*)d_in[3];
    const float* W2 = (const float*)d_in[4];
    const float* b2 = (const float*)d_in[5];
    float* out = (float*)d_out;

    const int N = N_NODES;
    const int E = in_sizes[1] / 2;
    const int* src = ei;
    const int* dst = ei + E;

    char* ws = (char*)d_ws;
    size_t off = 0;
    auto alloc = [&](size_t bytes) {
        char* p = ws + off;
        off = (off + bytes + 255) & ~(size_t)255;
        return p;
    };
    int*    bcur   = (int*)alloc(NBUCKETS * 4);
    int*    rs     = (int*)alloc(N * 4);
    int*    cnt    = (int*)alloc(N * 4);
    float*  dinv   = (float*)alloc(N * 4);
    short8* W1f    = (short8*)alloc(4096 * 16);
    short8* W2f    = (short8*)alloc(1024 * 16);
    uint*   ebuf   = (uint*)alloc((size_t)NBUCKETS * BCAP * 4);   // 9.6 MB
    int*    ssrc   = (int*)alloc((size_t)NBUCKETS * BCAP * 4);    // 9.6 MB
    uint*   h1     = (uint*)alloc((size_t)N * 64 * 4);            // 128 bf16/row
    uint*   h1a    = (uint*)alloc((size_t)N * 64 * 4);
    ushort* h2     = (ushort*)h1;                                 // h1 dead after agg1

    const int nScatBlocks = (E + EPB - 1) / EPB;         // 391
    const int nAggBlocks  = (N + 3) / 4;
    const int nTiles      = (N + 127) / 128;             // 782

    hipMemsetAsync(bcur, 0, NBUCKETS * 4, stream);
    wprep_kernel<<<20, 256, 0, stream>>>(W1, W2, W1f, W2f);

    bucket_scatter_kernel<<<nScatBlocks, 256, 0, stream>>>(src, dst, bcur, ebuf, E);
    bucket_sort_kernel<<<NBUCKETS, 256, 0, stream>>>(ebuf, bcur, ssrc, rs, cnt, dinv, N);

    gemm1_kernel<<<dim3(nTiles, 2), 512, 0, stream>>>(x, W1f, dinv, (ushort*)h1, N);
    agg1_kernel<<<nAggBlocks, 256, 0, stream>>>((const uint4*)h1, rs, cnt, ssrc, dinv, b1,
                                                (uint4*)h1a, N);
    gemm2_kernel<<<nTiles, 512, 0, stream>>>((const ushort*)h1a, W2f, dinv, h2, N);
    agg2_kernel<<<nAggBlocks, 256, 0, stream>>>((const uint2*)h2, rs, cnt, ssrc, dinv, b2,
                                                (float4*)out, N);
}

// Round 3
// 411.744 us; speedup vs baseline: 1.0852x; 1.0852x over previous
//
#include <hip/hip_runtime.h>
#include <hip/hip_bf16.h>

// GCN 2-layer: out = log_softmax(GCN2(relu(GCN1(x))))
// Round 10: Little's-law fix for gemm1. R8/R9 proved occupancy is NOT the
// bottleneck (doubled occupancy, got slower). Model that fits all data:
// the 1-deep prefetch keeps only 32 B/wave in flight -> Little's law caps
// the kernel at ~650 GB/s (matches measured FETCH rate exactly at ~500cyc
// L3-hit latency). R10: prefetch the ENTIRE 256-float A slice as 16
// back-to-back float4 loads (256 B/wave in flight, 8x MLP). Reverted to
// R7 full-N shape (x fetched once, acc[8]). v[16]=64 VGPR + 32 AGPR +
// misc ~= 117 unified regs -> 4-waves/SIMD band, __launch_bounds__(512,4)
// (128-reg cap, no forced spill -- R8's lesson).
// gemm2 already full-prefetches its A row. Aggs/sort unchanged.

#define N_NODES 100000
#define F_IN 256
#define F_MID 128
#define F_OUT 64

#define BSHIFT 8                      // 256 nodes per bucket
#define BNODES 256
#define NBUCKETS ((N_NODES + BNODES - 1) / BNODES)   // 391
#define BCAP 6144                     // mean 4096, sigma ~64 -> +32 sigma
#define EPB 4096                      // edges per scatter block

typedef __attribute__((ext_vector_type(8))) short short8;
typedef __attribute__((ext_vector_type(4))) float f32x4;

__device__ inline ushort bf16_rne(float f) {
    uint u = __float_as_uint(f);
    u += 0x7FFF + ((u >> 16) & 1);
    return (ushort)(u >> 16);
}
__device__ inline float lo16(uint r) { return __uint_as_float(r << 16); }
__device__ inline float hi16(uint r) { return __uint_as_float(r & 0xffff0000u); }
__device__ inline uint pack_bf2(float a, float b) {
    return (uint)bf16_rne(a) | ((uint)bf16_rne(b) << 16);
}

// ---------------- two-level bucket sort ----------------

// S1: block-binned scatter. packed = (dst&255)<<17 | src  (25 bits)
__global__ __launch_bounds__(256)
void bucket_scatter_kernel(const int* __restrict__ src, const int* __restrict__ dst,
                           int* __restrict__ bcur, uint* __restrict__ ebuf, int E) {
    __shared__ int curL[NBUCKETS];
    int t = threadIdx.x;
    int e0 = blockIdx.x * EPB;
    int e1 = e0 + EPB; if (e1 > E) e1 = E;

    for (int i = t; i < NBUCKETS; i += 256) curL[i] = 0;
    __syncthreads();
    for (int i = e0 + t; i < e1; i += 256) atomicAdd(&curL[dst[i] >> BSHIFT], 1);
    __syncthreads();
    for (int i = t; i < NBUCKETS; i += 256) {
        int h = curL[i];
        curL[i] = h ? atomicAdd(&bcur[i], h) : 0;
    }
    __syncthreads();
    for (int i = e0 + t; i < e1; i += 256) {
        int d = dst[i], s = src[i];
        int b = d >> BSHIFT;
        int pos = atomicAdd(&curL[b], 1);
        if (pos < BCAP) ebuf[(size_t)b * BCAP + pos] = ((uint)(d & (BNODES - 1)) << 17) | (uint)s;
    }
}

// S2: per-bucket counting sort; emits ssrc + rs + cnt + dinv.
__global__ __launch_bounds__(256)
void bucket_sort_kernel(const uint* __restrict__ ebuf, const int* __restrict__ bcur,
                        int* __restrict__ ssrc, int* __restrict__ rs, int* __restrict__ cnt,
                        float* __restrict__ dinv, int n) {
    __shared__ uint eL[BCAP];          // 24 KB
    __shared__ int hist[BNODES], ps[BNODES];
    int b = blockIdx.x, t = threadIdx.x;
    int nb = bcur[b];
    if (nb > BCAP) nb = BCAP;
    for (int i = t; i < nb; i += 256) eL[i] = ebuf[(size_t)b * BCAP + i];
    hist[t] = 0;
    __syncthreads();
    for (int i = t; i < nb; i += 256) atomicAdd(&hist[eL[i] >> 17], 1);
    __syncthreads();
    ps[t] = hist[t];
    __syncthreads();
#pragma unroll
    for (int off = 1; off < BNODES; off <<= 1) {
        int v = (t >= off) ? ps[t - off] : 0;
        __syncthreads();
        ps[t] += v;
        __syncthreads();
    }
    int excl = ps[t] - hist[t];
    int node = b * BNODES + t;
    if (node < n) {
        rs[node] = b * BCAP + excl;
        cnt[node] = hist[t];
        dinv[node] = 1.0f / sqrtf((float)hist[t] + 1.0f);
    }
    __syncthreads();
    ps[t] = excl;                      // reuse as running cursor
    __syncthreads();
    for (int i = t; i < nb; i += 256) {
        uint e = eL[i];
        int d = e >> 17;
        int p = atomicAdd(&ps[d], 1);
        ssrc[(size_t)b * BCAP + p] = (int)(e & 0x1FFFF);
    }
}

// ---------------- weight prep: fragment-ordered bf16 ----------------
// mfma_f32_16x16x32_bf16 B-frag: lane holds B[k=(lane>>4)*8+j][n=lane&15].
__global__ __launch_bounds__(256)
void wprep_kernel(const float* __restrict__ W1, const float* __restrict__ W2,
                  short8* __restrict__ W1f, short8* __restrict__ W2f) {
    int b = blockIdx.x;
    if (b < 16) {
        int f = b * 256 + threadIdx.x;
        int k0 = f >> 9, nt = (f >> 6) & 7, ln = f & 63;
        int kbase = k0 * 32 + (ln >> 4) * 8;
        int n = nt * 16 + (ln & 15);
        short8 fr;
#pragma unroll
        for (int j = 0; j < 8; ++j) fr[j] = (short)bf16_rne(W1[(kbase + j) * F_MID + n]);
        W1f[f] = fr;
    } else {
        int f = (b - 16) * 256 + threadIdx.x;
        int k0 = f >> 8, nt = (f >> 6) & 3, ln = f & 63;
        int kbase = k0 * 32 + (ln >> 4) * 8;
        int n = nt * 16 + (ln & 15);
        short8 fr;
#pragma unroll
        for (int j = 0; j < 8; ++j) fr[j] = (short)bf16_rne(W2[(kbase + j) * F_OUT + n]);
        W2f[f] = fr;
    }
}

// ---------------- MFMA GEMMs ----------------
// A: lane holds A[m=lane&15][k=(lane>>4)*8+j]; C/D: col=lane&15, row=(lane>>4)*4+reg.

// h1s[M,128](bf16) = dinv[m] * (x[M,256](fp32) @ W1bf16)
// 8 waves x 16 rows = 128-row tile; full A-row prefetch (16 float4 in
// flight per lane) for MLP; counted vmcnt drains while MFMAs run.
__global__ __launch_bounds__(512, 4)
void gemm1_kernel(const float* __restrict__ A, const short8* __restrict__ Wf,
                  const float* __restrict__ dinv, ushort* __restrict__ C,
                  int M) {
    __shared__ short8 BsF[4096];   // 64 KB
    int tid = threadIdx.x;
    int lane = tid & 63, w = tid >> 6;        // w in 0..7
    for (int f = tid; f < 4096; f += 512) BsF[f] = Wf[f];
    __syncthreads();

    const float4 z4 = make_float4(0.f, 0.f, 0.f, 0.f);
    int m0 = blockIdx.x * 128 + w * 16;
    int m = m0 + (lane & 15);
    bool mOk = (m < M);
    const float4* aptr = (const float4*)&A[(size_t)(mOk ? m : 0) * F_IN + (lane >> 4) * 8];

    f32x4 acc[8];
#pragma unroll
    for (int nt = 0; nt < 8; ++nt) acc[nt] = (f32x4){0.f, 0.f, 0.f, 0.f};

    // Full-slice prefetch: 16 loads issued back-to-back, 256 B/lane-slice
    // in flight. v[2k+j] = aptr[8k + j].
    float4 v[16];
#pragma unroll
    for (int k0 = 0; k0 < 8; ++k0) {
        v[2 * k0 + 0] = mOk ? aptr[k0 * 8 + 0] : z4;
        v[2 * k0 + 1] = mOk ? aptr[k0 * 8 + 1] : z4;
    }

#pragma unroll
    for (int k0 = 0; k0 < 8; ++k0) {
        short8 af;
        af[0] = (short)bf16_rne(v[2 * k0].x);     af[1] = (short)bf16_rne(v[2 * k0].y);
        af[2] = (short)bf16_rne(v[2 * k0].z);     af[3] = (short)bf16_rne(v[2 * k0].w);
        af[4] = (short)bf16_rne(v[2 * k0 + 1].x); af[5] = (short)bf16_rne(v[2 * k0 + 1].y);
        af[6] = (short)bf16_rne(v[2 * k0 + 1].z); af[7] = (short)bf16_rne(v[2 * k0 + 1].w);
#pragma unroll
        for (int nt = 0; nt < 8; ++nt) {
            short8 bfr = BsF[(k0 * 8 + nt) * 64 + lane];
            acc[nt] = __builtin_amdgcn_mfma_f32_16x16x32_bf16(af, bfr, acc[nt], 0, 0, 0);
        }
    }
#pragma unroll
    for (int i = 0; i < 4; ++i) {
        int r = m0 + (lane >> 4) * 4 + i;
        if (r < M) {
            float dv = dinv[r];
#pragma unroll
            for (int nt = 0; nt < 8; ++nt)
                C[(size_t)r * F_MID + nt * 16 + (lane & 15)] = bf16_rne(dv * acc[nt][i]);
        }
    }
}

// h2s[M,64](bf16) = dinv[m] * (h1a[M,128](bf16) @ W2bf16)
__global__ __launch_bounds__(512, 4)
void gemm2_kernel(const ushort* __restrict__ A, const short8* __restrict__ Wf,
                  const float* __restrict__ dinv, ushort* __restrict__ C,
                  int M) {
    __shared__ short8 BsF[1024];   // 16 KB
    int tid = threadIdx.x;
    int lane = tid & 63, w = tid >> 6;
    for (int f = tid; f < 1024; f += 512) BsF[f] = Wf[f];
    __syncthreads();

    int m0 = blockIdx.x * 128 + w * 16;
    int m = m0 + (lane & 15);
    bool mOk = (m < M);

    f32x4 acc[4];
#pragma unroll
    for (int nt = 0; nt < 4; ++nt) acc[nt] = (f32x4){0.f, 0.f, 0.f, 0.f};

    short8 afr[4];
#pragma unroll
    for (int k0 = 0; k0 < 4; ++k0) {
        short8 af = (short8){0, 0, 0, 0, 0, 0, 0, 0};
        if (mOk) af = *(const short8*)&A[(size_t)m * F_MID + k0 * 32 + (lane >> 4) * 8];
        afr[k0] = af;
    }
#pragma unroll
    for (int k0 = 0; k0 < 4; ++k0)
#pragma unroll
        for (int nt = 0; nt < 4; ++nt) {
            short8 bfr = BsF[(k0 * 4 + nt) * 64 + lane];
            acc[nt] = __builtin_amdgcn_mfma_f32_16x16x32_bf16(afr[k0], bfr, acc[nt], 0, 0, 0);
        }
#pragma unroll
    for (int i = 0; i < 4; ++i) {
        int r = m0 + (lane >> 4) * 4 + i;
        if (r < M) {
            float dv = dinv[r];
#pragma unroll
            for (int nt = 0; nt < 4; ++nt)
                C[(size_t)r * F_OUT + nt * 16 + (lane & 15)] = bf16_rne(dv * acc[nt][i]);
        }
    }
}

// ---------------- aggregation ----------------
// agg1: rows pre-scaled by dinv[src]. One wave/node; quarter q handles edge
// base+q and base+4+q (x2 unroll -> 8 gathers in flight); 16 lanes x uint4
// (16B) cover the 256-B row; butterfly fold at end.
__global__ __launch_bounds__(256)
void agg1_kernel(const uint4* __restrict__ h, const int* __restrict__ rs,
                 const int* __restrict__ cnt, const int* __restrict__ ssrc,
                 const float* __restrict__ dinv, const float* __restrict__ bias,
                 uint4* __restrict__ outp, int n) {
    int w = threadIdx.x >> 6, lane = threadIdx.x & 63;
    int node = blockIdx.x * 4 + w;
    if (node >= n) return;
    int q = lane >> 4, c16 = lane & 15;
    int start = rs[node], c = cnt[node];
    float dn = dinv[node];
    float a[8];
#pragma unroll
    for (int i = 0; i < 8; ++i) a[i] = 0.f;

    for (int base = 0; base < c; base += 8) {
        int e0 = base + q, e1 = base + 4 + q;
        bool p0 = e0 < c, p1 = e1 < c;
        uint4 r0, r1;
        int s0 = 0, s1 = 0;
        if (p0) s0 = ssrc[start + e0];
        if (p1) s1 = ssrc[start + e1];
        if (p0) r0 = h[(size_t)s0 * 16 + c16];
        if (p1) r1 = h[(size_t)s1 * 16 + c16];
        if (p0) {
            a[0] += lo16(r0.x); a[1] += hi16(r0.x);
            a[2] += lo16(r0.y); a[3] += hi16(r0.y);
            a[4] += lo16(r0.z); a[5] += hi16(r0.z);
            a[6] += lo16(r0.w); a[7] += hi16(r0.w);
        }
        if (p1) {
            a[0] += lo16(r1.x); a[1] += hi16(r1.x);
            a[2] += lo16(r1.y); a[3] += hi16(r1.y);
            a[4] += lo16(r1.z); a[5] += hi16(r1.z);
            a[6] += lo16(r1.w); a[7] += hi16(r1.w);
        }
    }
#pragma unroll
    for (int i = 0; i < 8; ++i) {
        a[i] += __shfl_xor(a[i], 16);
        a[i] += __shfl_xor(a[i], 32);
    }
    uint4 sr = h[(size_t)node * 16 + c16];
    const float4* b4 = (const float4*)bias;
    float4 b0 = b4[c16 * 2], b1 = b4[c16 * 2 + 1];
    float o0 = fmaxf(fmaf(dn, a[0] + lo16(sr.x), b0.x), 0.f);
    float o1 = fmaxf(fmaf(dn, a[1] + hi16(sr.x), b0.y), 0.f);
    float o2 = fmaxf(fmaf(dn, a[2] + lo16(sr.y), b0.z), 0.f);
    float o3 = fmaxf(fmaf(dn, a[3] + hi16(sr.y), b0.w), 0.f);
    float o4 = fmaxf(fmaf(dn, a[4] + lo16(sr.z), b1.x), 0.f);
    float o5 = fmaxf(fmaf(dn, a[5] + hi16(sr.z), b1.y), 0.f);
    float o6 = fmaxf(fmaf(dn, a[6] + lo16(sr.w), b1.z), 0.f);
    float o7 = fmaxf(fmaf(dn, a[7] + hi16(sr.w), b1.w), 0.f);
    if (q == 0) {
        uint4 ov;
        ov.x = pack_bf2(o0, o1);
        ov.y = pack_bf2(o2, o3);
        ov.z = pack_bf2(o4, o5);
        ov.w = pack_bf2(o6, o7);
        outp[(size_t)node * 16 + c16] = ov;
    }
}

// agg2: 64-col bf16 rows (128 B), 16 lanes x uint2; x2-unrolled gather;
// fused bias + log_softmax.
__global__ __launch_bounds__(256)
void agg2_kernel(const uint2* __restrict__ h, const int* __restrict__ rs,
                 const int* __restrict__ cnt, const int* __restrict__ ssrc,
                 const float* __restrict__ dinv, const float* __restrict__ bias,
                 float4* __restrict__ out4, int n) {
    int w = threadIdx.x >> 6, lane = threadIdx.x & 63;
    int node = blockIdx.x * 4 + w;
    if (node >= n) return;
    int q = lane >> 4, c16 = lane & 15;
    int start = rs[node], c = cnt[node];
    float dn = dinv[node];
    float a[4];
#pragma unroll
    for (int i = 0; i < 4; ++i) a[i] = 0.f;

    for (int base = 0; base < c; base += 8) {
        int e0 = base + q, e1 = base + 4 + q;
        bool p0 = e0 < c, p1 = e1 < c;
        uint2 r0, r1;
        int s0 = 0, s1 = 0;
        if (p0) s0 = ssrc[start + e0];
        if (p1) s1 = ssrc[start + e1];
        if (p0) r0 = h[(size_t)s0 * 16 + c16];
        if (p1) r1 = h[(size_t)s1 * 16 + c16];
        if (p0) {
            a[0] += lo16(r0.x); a[1] += hi16(r0.x);
            a[2] += lo16(r0.y); a[3] += hi16(r0.y);
        }
        if (p1) {
            a[0] += lo16(r1.x); a[1] += hi16(r1.x);
            a[2] += lo16(r1.y); a[3] += hi16(r1.y);
        }
    }
#pragma unroll
    for (int i = 0; i < 4; ++i) {
        a[i] += __shfl_xor(a[i], 16);
        a[i] += __shfl_xor(a[i], 32);
    }
    uint2 sr = h[(size_t)node * 16 + c16];
    float4 bv = ((const float4*)bias)[c16];
    float v0 = fmaf(dn, a[0] + lo16(sr.x), bv.x);
    float v1 = fmaf(dn, a[1] + hi16(sr.x), bv.y);
    float v2 = fmaf(dn, a[2] + lo16(sr.y), bv.z);
    float v3 = fmaf(dn, a[3] + hi16(sr.y), bv.w);
    float m = fmaxf(fmaxf(v0, v1), fmaxf(v2, v3));
#pragma unroll
    for (int off = 1; off < 16; off <<= 1) m = fmaxf(m, __shfl_xor(m, off));
    float ssum = expf(v0 - m) + expf(v1 - m) + expf(v2 - m) + expf(v3 - m);
#pragma unroll
    for (int off = 1; off < 16; off <<= 1) ssum += __shfl_xor(ssum, off);
    float lg = m + logf(ssum);
    if (q == 0) out4[(size_t)node * 16 + c16] = make_float4(v0 - lg, v1 - lg, v2 - lg, v3 - lg);
}

// ---------------- launch ----------------

extern "C" void kernel_launch(void* const* d_in, const int* in_sizes, int n_in,
                              void* d_out, int out_size, void* d_ws, size_t ws_size,
                              hipStream_t stream) {
    const float* x  = (const float*)d_in[0];
    const int*   ei = (const int*)d_in[1];
    const float* W1 = (const float*)d_in[2];
    const float* b1 = (const float*)d_in[3];
    const float* W2 = (const float*)d_in[4];
    const float* b2 = (const float*)d_in[5];
    float* out = (float*)d_out;

    const int N = N_NODES;
    const int E = in_sizes[1] / 2;
    const int* src = ei;
    const int* dst = ei + E;

    char* ws = (char*)d_ws;
    size_t off = 0;
    auto alloc = [&](size_t bytes) {
        char* p = ws + off;
        off = (off + bytes + 255) & ~(size_t)255;
        return p;
    };
    int*    bcur   = (int*)alloc(NBUCKETS * 4);
    int*    rs     = (int*)alloc(N * 4);
    int*    cnt    = (int*)alloc(N * 4);
    float*  dinv   = (float*)alloc(N * 4);
    short8* W1f    = (short8*)alloc(4096 * 16);
    short8* W2f    = (short8*)alloc(1024 * 16);
    uint*   ebuf   = (uint*)alloc((size_t)NBUCKETS * BCAP * 4);   // 9.6 MB
    int*    ssrc   = (int*)alloc((size_t)NBUCKETS * BCAP * 4);    // 9.6 MB
    uint*   h1     = (uint*)alloc((size_t)N * 64 * 4);            // 128 bf16/row
    uint*   h1a    = (uint*)alloc((size_t)N * 64 * 4);
    ushort* h2     = (ushort*)h1;                                 // h1 dead after agg1

    const int nScatBlocks = (E + EPB - 1) / EPB;         // 391
    const int nAggBlocks  = (N + 3) / 4;
    const int nTiles      = (N + 127) / 128;             // 782

    hipMemsetAsync(bcur, 0, NBUCKETS * 4, stream);
    wprep_kernel<<<20, 256, 0, stream>>>(W1, W2, W1f, W2f);

    bucket_scatter_kernel<<<nScatBlocks, 256, 0, stream>>>(src, dst, bcur, ebuf, E);
    bucket_sort_kernel<<<NBUCKETS, 256, 0, stream>>>(ebuf, bcur, ssrc, rs, cnt, dinv, N);

    gemm1_kernel<<<nTiles, 512, 0, stream>>>(x, W1f, dinv, (ushort*)h1, N);
    agg1_kernel<<<nAggBlocks, 256, 0, stream>>>((const uint4*)h1, rs, cnt, ssrc, dinv, b1,
                                                (uint4*)h1a, N);
    gemm2_kernel<<<nTiles, 512, 0, stream>>>((const ushort*)h1a, W2f, dinv, h2, N);
    agg2_kernel<<<nAggBlocks, 256, 0, stream>>>((const uint2*)h2, rs, cnt, ssrc, dinv, b2,
                                                (float4*)out, N);
}

// Round 5
// 391.564 us; speedup vs baseline: 1.1411x; 1.0515x over previous
//
#include <hip/hip_runtime.h>
#include <hip/hip_bf16.h>

// GCN 2-layer: out = log_softmax(GCN2(relu(GCN1(x))))
// Round 12: R11 retry. The float4 "+v" fence didn't compile (backend can't
// tie 128-bit indirect register tuples). Fix: fence the four 32-bit scalar
// components instead -- supported idiom, same semantics (volatile asm pins
// position; all 16 A-row loads must issue before the k-loop -> 256 B/lane
// in flight, one amortized latency stall instead of 16).
// agg1/agg2 keep the x4 gather unroll (16 rows in flight/wave).
// gemm2/sort unchanged.

#define N_NODES 100000
#define F_IN 256
#define F_MID 128
#define F_OUT 64

#define BSHIFT 8                      // 256 nodes per bucket
#define BNODES 256
#define NBUCKETS ((N_NODES + BNODES - 1) / BNODES)   // 391
#define BCAP 6144                     // mean 4096, sigma ~64 -> +32 sigma
#define EPB 4096                      // edges per scatter block

typedef __attribute__((ext_vector_type(8))) short short8;
typedef __attribute__((ext_vector_type(4))) float f32x4;

__device__ inline ushort bf16_rne(float f) {
    uint u = __float_as_uint(f);
    u += 0x7FFF + ((u >> 16) & 1);
    return (ushort)(u >> 16);
}
__device__ inline float lo16(uint r) { return __uint_as_float(r << 16); }
__device__ inline float hi16(uint r) { return __uint_as_float(r & 0xffff0000u); }
__device__ inline uint pack_bf2(float a, float b) {
    return (uint)bf16_rne(a) | ((uint)bf16_rne(b) << 16);
}

// ---------------- two-level bucket sort ----------------

// S1: block-binned scatter. packed = (dst&255)<<17 | src  (25 bits)
__global__ __launch_bounds__(256)
void bucket_scatter_kernel(const int* __restrict__ src, const int* __restrict__ dst,
                           int* __restrict__ bcur, uint* __restrict__ ebuf, int E) {
    __shared__ int curL[NBUCKETS];
    int t = threadIdx.x;
    int e0 = blockIdx.x * EPB;
    int e1 = e0 + EPB; if (e1 > E) e1 = E;

    for (int i = t; i < NBUCKETS; i += 256) curL[i] = 0;
    __syncthreads();
    for (int i = e0 + t; i < e1; i += 256) atomicAdd(&curL[dst[i] >> BSHIFT], 1);
    __syncthreads();
    for (int i = t; i < NBUCKETS; i += 256) {
        int h = curL[i];
        curL[i] = h ? atomicAdd(&bcur[i], h) : 0;
    }
    __syncthreads();
    for (int i = e0 + t; i < e1; i += 256) {
        int d = dst[i], s = src[i];
        int b = d >> BSHIFT;
        int pos = atomicAdd(&curL[b], 1);
        if (pos < BCAP) ebuf[(size_t)b * BCAP + pos] = ((uint)(d & (BNODES - 1)) << 17) | (uint)s;
    }
}

// S2: per-bucket counting sort; emits ssrc + rs + cnt + dinv.
__global__ __launch_bounds__(256)
void bucket_sort_kernel(const uint* __restrict__ ebuf, const int* __restrict__ bcur,
                        int* __restrict__ ssrc, int* __restrict__ rs, int* __restrict__ cnt,
                        float* __restrict__ dinv, int n) {
    __shared__ uint eL[BCAP];          // 24 KB
    __shared__ int hist[BNODES], ps[BNODES];
    int b = blockIdx.x, t = threadIdx.x;
    int nb = bcur[b];
    if (nb > BCAP) nb = BCAP;
    for (int i = t; i < nb; i += 256) eL[i] = ebuf[(size_t)b * BCAP + i];
    hist[t] = 0;
    __syncthreads();
    for (int i = t; i < nb; i += 256) atomicAdd(&hist[eL[i] >> 17], 1);
    __syncthreads();
    ps[t] = hist[t];
    __syncthreads();
#pragma unroll
    for (int off = 1; off < BNODES; off <<= 1) {
        int v = (t >= off) ? ps[t - off] : 0;
        __syncthreads();
        ps[t] += v;
        __syncthreads();
    }
    int excl = ps[t] - hist[t];
    int node = b * BNODES + t;
    if (node < n) {
        rs[node] = b * BCAP + excl;
        cnt[node] = hist[t];
        dinv[node] = 1.0f / sqrtf((float)hist[t] + 1.0f);
    }
    __syncthreads();
    ps[t] = excl;                      // reuse as running cursor
    __syncthreads();
    for (int i = t; i < nb; i += 256) {
        uint e = eL[i];
        int d = e >> 17;
        int p = atomicAdd(&ps[d], 1);
        ssrc[(size_t)b * BCAP + p] = (int)(e & 0x1FFFF);
    }
}

// ---------------- weight prep: fragment-ordered bf16 ----------------
// mfma_f32_16x16x32_bf16 B-frag: lane holds B[k=(lane>>4)*8+j][n=lane&15].
__global__ __launch_bounds__(256)
void wprep_kernel(const float* __restrict__ W1, const float* __restrict__ W2,
                  short8* __restrict__ W1f, short8* __restrict__ W2f) {
    int b = blockIdx.x;
    if (b < 16) {
        int f = b * 256 + threadIdx.x;
        int k0 = f >> 9, nt = (f >> 6) & 7, ln = f & 63;
        int kbase = k0 * 32 + (ln >> 4) * 8;
        int n = nt * 16 + (ln & 15);
        short8 fr;
#pragma unroll
        for (int j = 0; j < 8; ++j) fr[j] = (short)bf16_rne(W1[(kbase + j) * F_MID + n]);
        W1f[f] = fr;
    } else {
        int f = (b - 16) * 256 + threadIdx.x;
        int k0 = f >> 8, nt = (f >> 6) & 3, ln = f & 63;
        int kbase = k0 * 32 + (ln >> 4) * 8;
        int n = nt * 16 + (ln & 15);
        short8 fr;
#pragma unroll
        for (int j = 0; j < 8; ++j) fr[j] = (short)bf16_rne(W2[(kbase + j) * F_OUT + n]);
        W2f[f] = fr;
    }
}

// ---------------- MFMA GEMMs ----------------
// A: lane holds A[m=lane&15][k=(lane>>4)*8+j]; C/D: col=lane&15, row=(lane>>4)*4+reg.

// h1s[M,128](bf16) = dinv[m] * (x[M,256](fp32) @ W1bf16)
// 8 waves x 16 rows = 128-row tile; full A-row prefetch (16 float4, 256B
// per lane in flight) enforced by per-component asm fences.
__global__ __launch_bounds__(512, 4)
void gemm1_kernel(const float* __restrict__ A, const short8* __restrict__ Wf,
                  const float* __restrict__ dinv, ushort* __restrict__ C,
                  int M) {
    __shared__ short8 BsF[4096];   // 64 KB
    int tid = threadIdx.x;
    int lane = tid & 63, w = tid >> 6;        // w in 0..7
    for (int f = tid; f < 4096; f += 512) BsF[f] = Wf[f];
    __syncthreads();

    const float4 z4 = make_float4(0.f, 0.f, 0.f, 0.f);
    int m0 = blockIdx.x * 128 + w * 16;
    int m = m0 + (lane & 15);
    bool mOk = (m < M);
    const float4* aptr = (const float4*)&A[(size_t)(mOk ? m : 0) * F_IN + (lane >> 4) * 8];

    f32x4 acc[8];
#pragma unroll
    for (int nt = 0; nt < 8; ++nt) acc[nt] = (f32x4){0.f, 0.f, 0.f, 0.f};

    // Full-slice prefetch: 16 loads, then per-component register fences so
    // the compiler CANNOT sink them (R10's failure). All 16 in flight.
    float4 v[16];
#pragma unroll
    for (int i = 0; i < 16; ++i) v[i] = mOk ? aptr[(i >> 1) * 8 + (i & 1)] : z4;
#pragma unroll
    for (int i = 0; i < 16; ++i)
        asm volatile("" : "+v"(v[i].x), "+v"(v[i].y), "+v"(v[i].z), "+v"(v[i].w));

#pragma unroll
    for (int k0 = 0; k0 < 8; ++k0) {
        short8 af;
        af[0] = (short)bf16_rne(v[2 * k0].x);     af[1] = (short)bf16_rne(v[2 * k0].y);
        af[2] = (short)bf16_rne(v[2 * k0].z);     af[3] = (short)bf16_rne(v[2 * k0].w);
        af[4] = (short)bf16_rne(v[2 * k0 + 1].x); af[5] = (short)bf16_rne(v[2 * k0 + 1].y);
        af[6] = (short)bf16_rne(v[2 * k0 + 1].z); af[7] = (short)bf16_rne(v[2 * k0 + 1].w);
#pragma unroll
        for (int nt = 0; nt < 8; ++nt) {
            short8 bfr = BsF[(k0 * 8 + nt) * 64 + lane];
            acc[nt] = __builtin_amdgcn_mfma_f32_16x16x32_bf16(af, bfr, acc[nt], 0, 0, 0);
        }
    }
#pragma unroll
    for (int i = 0; i < 4; ++i) {
        int r = m0 + (lane >> 4) * 4 + i;
        if (r < M) {
            float dv = dinv[r];
#pragma unroll
            for (int nt = 0; nt < 8; ++nt)
                C[(size_t)r * F_MID + nt * 16 + (lane & 15)] = bf16_rne(dv * acc[nt][i]);
        }
    }
}

// h2s[M,64](bf16) = dinv[m] * (h1a[M,128](bf16) @ W2bf16)
__global__ __launch_bounds__(512, 4)
void gemm2_kernel(const ushort* __restrict__ A, const short8* __restrict__ Wf,
                  const float* __restrict__ dinv, ushort* __restrict__ C,
                  int M) {
    __shared__ short8 BsF[1024];   // 16 KB
    int tid = threadIdx.x;
    int lane = tid & 63, w = tid >> 6;
    for (int f = tid; f < 1024; f += 512) BsF[f] = Wf[f];
    __syncthreads();

    int m0 = blockIdx.x * 128 + w * 16;
    int m = m0 + (lane & 15);
    bool mOk = (m < M);

    f32x4 acc[4];
#pragma unroll
    for (int nt = 0; nt < 4; ++nt) acc[nt] = (f32x4){0.f, 0.f, 0.f, 0.f};

    short8 afr[4];
#pragma unroll
    for (int k0 = 0; k0 < 4; ++k0) {
        short8 af = (short8){0, 0, 0, 0, 0, 0, 0, 0};
        if (mOk) af = *(const short8*)&A[(size_t)m * F_MID + k0 * 32 + (lane >> 4) * 8];
        afr[k0] = af;
    }
#pragma unroll
    for (int k0 = 0; k0 < 4; ++k0)
#pragma unroll
        for (int nt = 0; nt < 4; ++nt) {
            short8 bfr = BsF[(k0 * 4 + nt) * 64 + lane];
            acc[nt] = __builtin_amdgcn_mfma_f32_16x16x32_bf16(afr[k0], bfr, acc[nt], 0, 0, 0);
        }
#pragma unroll
    for (int i = 0; i < 4; ++i) {
        int r = m0 + (lane >> 4) * 4 + i;
        if (r < M) {
            float dv = dinv[r];
#pragma unroll
            for (int nt = 0; nt < 4; ++nt)
                C[(size_t)r * F_OUT + nt * 16 + (lane & 15)] = bf16_rne(dv * acc[nt][i]);
        }
    }
}

// ---------------- aggregation ----------------
// agg1: rows pre-scaled by dinv[src]. One wave/node; quarter q handles edges
// base+4j+q, j=0..3 (x4 unroll -> 16 gathers in flight); 16 lanes x uint4
// (16B) cover the 256-B row; butterfly fold at end.
__global__ __launch_bounds__(256)
void agg1_kernel(const uint4* __restrict__ h, const int* __restrict__ rs,
                 const int* __restrict__ cnt, const int* __restrict__ ssrc,
                 const float* __restrict__ dinv, const float* __restrict__ bias,
                 uint4* __restrict__ outp, int n) {
    int w = threadIdx.x >> 6, lane = threadIdx.x & 63;
    int node = blockIdx.x * 4 + w;
    if (node >= n) return;
    int q = lane >> 4, c16 = lane & 15;
    int start = rs[node], c = cnt[node];
    float dn = dinv[node];
    float a[8];
#pragma unroll
    for (int i = 0; i < 8; ++i) a[i] = 0.f;

    for (int base = 0; base < c; base += 16) {
        bool p[4];
        int s[4];
        uint4 r[4];
#pragma unroll
        for (int j = 0; j < 4; ++j) {
            int e = base + j * 4 + q;
            p[j] = e < c;
            if (p[j]) s[j] = ssrc[start + e];
        }
#pragma unroll
        for (int j = 0; j < 4; ++j)
            if (p[j]) r[j] = h[(size_t)s[j] * 16 + c16];
#pragma unroll
        for (int j = 0; j < 4; ++j) {
            if (p[j]) {
                a[0] += lo16(r[j].x); a[1] += hi16(r[j].x);
                a[2] += lo16(r[j].y); a[3] += hi16(r[j].y);
                a[4] += lo16(r[j].z); a[5] += hi16(r[j].z);
                a[6] += lo16(r[j].w); a[7] += hi16(r[j].w);
            }
        }
    }
#pragma unroll
    for (int i = 0; i < 8; ++i) {
        a[i] += __shfl_xor(a[i], 16);
        a[i] += __shfl_xor(a[i], 32);
    }
    uint4 sr = h[(size_t)node * 16 + c16];
    const float4* b4 = (const float4*)bias;
    float4 b0 = b4[c16 * 2], b1 = b4[c16 * 2 + 1];
    float o0 = fmaxf(fmaf(dn, a[0] + lo16(sr.x), b0.x), 0.f);
    float o1 = fmaxf(fmaf(dn, a[1] + hi16(sr.x), b0.y), 0.f);
    float o2 = fmaxf(fmaf(dn, a[2] + lo16(sr.y), b0.z), 0.f);
    float o3 = fmaxf(fmaf(dn, a[3] + hi16(sr.y), b0.w), 0.f);
    float o4 = fmaxf(fmaf(dn, a[4] + lo16(sr.z), b1.x), 0.f);
    float o5 = fmaxf(fmaf(dn, a[5] + hi16(sr.z), b1.y), 0.f);
    float o6 = fmaxf(fmaf(dn, a[6] + lo16(sr.w), b1.z), 0.f);
    float o7 = fmaxf(fmaf(dn, a[7] + hi16(sr.w), b1.w), 0.f);
    if (q == 0) {
        uint4 ov;
        ov.x = pack_bf2(o0, o1);
        ov.y = pack_bf2(o2, o3);
        ov.z = pack_bf2(o4, o5);
        ov.w = pack_bf2(o6, o7);
        outp[(size_t)node * 16 + c16] = ov;
    }
}

// agg2: 64-col bf16 rows (128 B), 16 lanes x uint2; x4-unrolled gather;
// fused bias + log_softmax.
__global__ __launch_bounds__(256)
void agg2_kernel(const uint2* __restrict__ h, const int* __restrict__ rs,
                 const int* __restrict__ cnt, const int* __restrict__ ssrc,
                 const float* __restrict__ dinv, const float* __restrict__ bias,
                 float4* __restrict__ out4, int n) {
    int w = threadIdx.x >> 6, lane = threadIdx.x & 63;
    int node = blockIdx.x * 4 + w;
    if (node >= n) return;
    int q = lane >> 4, c16 = lane & 15;
    int start = rs[node], c = cnt[node];
    float dn = dinv[node];
    float a[4];
#pragma unroll
    for (int i = 0; i < 4; ++i) a[i] = 0.f;

    for (int base = 0; base < c; base += 16) {
        bool p[4];
        int s[4];
        uint2 r[4];
#pragma unroll
        for (int j = 0; j < 4; ++j) {
            int e = base + j * 4 + q;
            p[j] = e < c;
            if (p[j]) s[j] = ssrc[start + e];
        }
#pragma unroll
        for (int j = 0; j < 4; ++j)
            if (p[j]) r[j] = h[(size_t)s[j] * 16 + c16];
#pragma unroll
        for (int j = 0; j < 4; ++j) {
            if (p[j]) {
                a[0] += lo16(r[j].x); a[1] += hi16(r[j].x);
                a[2] += lo16(r[j].y); a[3] += hi16(r[j].y);
            }
        }
    }
#pragma unroll
    for (int i = 0; i < 4; ++i) {
        a[i] += __shfl_xor(a[i], 16);
        a[i] += __shfl_xor(a[i], 32);
    }
    uint2 sr = h[(size_t)node * 16 + c16];
    float4 bv = ((const float4*)bias)[c16];
    float v0 = fmaf(dn, a[0] + lo16(sr.x), bv.x);
    float v1 = fmaf(dn, a[1] + hi16(sr.x), bv.y);
    float v2 = fmaf(dn, a[2] + lo16(sr.y), bv.z);
    float v3 = fmaf(dn, a[3] + hi16(sr.y), bv.w);
    float m = fmaxf(fmaxf(v0, v1), fmaxf(v2, v3));
#pragma unroll
    for (int off = 1; off < 16; off <<= 1) m = fmaxf(m, __shfl_xor(m, off));
    float ssum = expf(v0 - m) + expf(v1 - m) + expf(v2 - m) + expf(v3 - m);
#pragma unroll
    for (int off = 1; off < 16; off <<= 1) ssum += __shfl_xor(ssum, off);
    float lg = m + logf(ssum);
    if (q == 0) out4[(size_t)node * 16 + c16] = make_float4(v0 - lg, v1 - lg, v2 - lg, v3 - lg);
}

// ---------------- launch ----------------

extern "C" void kernel_launch(void* const* d_in, const int* in_sizes, int n_in,
                              void* d_out, int out_size, void* d_ws, size_t ws_size,
                              hipStream_t stream) {
    const float* x  = (const float*)d_in[0];
    const int*   ei = (const int*)d_in[1];
    const float* W1 = (const float*)d_in[2];
    const float* b1 = (const float*)d_in[3];
    const float* W2 = (const float*)d_in[4];
    const float* b2 = (const float*)d_in[5];
    float* out = (float*)d_out;

    const int N = N_NODES;
    const int E = in_sizes[1] / 2;
    const int* src = ei;
    const int* dst = ei + E;

    char* ws = (char*)d_ws;
    size_t off = 0;
    auto alloc = [&](size_t bytes) {
        char* p = ws + off;
        off = (off + bytes + 255) & ~(size_t)255;
        return p;
    };
    int*    bcur   = (int*)alloc(NBUCKETS * 4);
    int*    rs     = (int*)alloc(N * 4);
    int*    cnt    = (int*)alloc(N * 4);
    float*  dinv   = (float*)alloc(N * 4);
    short8* W1f    = (short8*)alloc(4096 * 16);
    short8* W2f    = (short8*)alloc(1024 * 16);
    uint*   ebuf   = (uint*)alloc((size_t)NBUCKETS * BCAP * 4);   // 9.6 MB
    int*    ssrc   = (int*)alloc((size_t)NBUCKETS * BCAP * 4);    // 9.6 MB
    uint*   h1     = (uint*)alloc((size_t)N * 64 * 4);            // 128 bf16/row
    uint*   h1a    = (uint*)alloc((size_t)N * 64 * 4);
    ushort* h2     = (ushort*)h1;                                 // h1 dead after agg1

    const int nScatBlocks = (E + EPB - 1) / EPB;         // 391
    const int nAggBlocks  = (N + 3) / 4;
    const int nTiles      = (N + 127) / 128;             // 782

    hipMemsetAsync(bcur, 0, NBUCKETS * 4, stream);
    wprep_kernel<<<20, 256, 0, stream>>>(W1, W2, W1f, W2f);

    bucket_scatter_kernel<<<nScatBlocks, 256, 0, stream>>>(src, dst, bcur, ebuf, E);
    bucket_sort_kernel<<<NBUCKETS, 256, 0, stream>>>(ebuf, bcur, ssrc, rs, cnt, dinv, N);

    gemm1_kernel<<<nTiles, 512, 0, stream>>>(x, W1f, dinv, (ushort*)h1, N);
    agg1_kernel<<<nAggBlocks, 256, 0, stream>>>((const uint4*)h1, rs, cnt, ssrc, dinv, b1,
                                                (uint4*)h1a, N);
    gemm2_kernel<<<nTiles, 512, 0, stream>>>((const ushort*)h1a, W2f, dinv, h2, N);
    agg2_kernel<<<nAggBlocks, 256, 0, stream>>>((const uint2*)h2, rs, cnt, ssrc, dinv, b2,
                                                (float4*)out, N);
}

// Round 6
// 374.147 us; speedup vs baseline: 1.1943x; 1.0466x over previous
//
#include <hip/hip_runtime.h>
#include <hip/hip_bf16.h>

// GCN 2-layer: out = log_softmax(GCN2(relu(GCN1(x))))
// Round 13: gemm1 rewritten as LDS-staged coalesced pipeline. R7-R12 data
// shows gemm1 pinned at 78us / 1.3 TB/s effective regardless of occupancy
// (R8/R9) or register prefetch depth (R10/R12 -- compiler defeats fences).
// Root cause reattributed to COALESCING: the A-frag load puts lanes 0-15 on
// 16 rows 1KB apart -> 16 scattered transactions per instruction ->
// transaction-rate bound. Fix:
//  - stage A per 64-col K-chunk into LDS with fully-coalesced loads
//    (adjacent lanes -> adjacent 16B),
//  - convert fp32->bf16 DURING staging; LDS holds MFMA-A-frag-ordered bf16
//    -> inner loop is ONE ds_read_b128 per A-frag, zero conversions,
//  - XOR swizzle (c ^ row&7) on both ds_write and ds_read (16-way conflict
//    -> free 2-way),
//  - double-buffered chunks, memory-clobber fence pins next-chunk loads
//    before compute.
// LDS 96 KB -> 1 block/CU (8 waves) -- occupancy is NOT the bottleneck
// (proven R8/R9). gemm2/aggs/sort frozen from R12 to isolate the delta.

#define N_NODES 100000
#define F_IN 256
#define F_MID 128
#define F_OUT 64

#define BSHIFT 8                      // 256 nodes per bucket
#define BNODES 256
#define NBUCKETS ((N_NODES + BNODES - 1) / BNODES)   // 391
#define BCAP 6144                     // mean 4096, sigma ~64 -> +32 sigma
#define EPB 4096                      // edges per scatter block

typedef __attribute__((ext_vector_type(8))) short short8;
typedef __attribute__((ext_vector_type(4))) float f32x4;

__device__ inline ushort bf16_rne(float f) {
    uint u = __float_as_uint(f);
    u += 0x7FFF + ((u >> 16) & 1);
    return (ushort)(u >> 16);
}
__device__ inline float lo16(uint r) { return __uint_as_float(r << 16); }
__device__ inline float hi16(uint r) { return __uint_as_float(r & 0xffff0000u); }
__device__ inline uint pack_bf2(float a, float b) {
    return (uint)bf16_rne(a) | ((uint)bf16_rne(b) << 16);
}

// ---------------- two-level bucket sort ----------------

// S1: block-binned scatter. packed = (dst&255)<<17 | src  (25 bits)
__global__ __launch_bounds__(256)
void bucket_scatter_kernel(const int* __restrict__ src, const int* __restrict__ dst,
                           int* __restrict__ bcur, uint* __restrict__ ebuf, int E) {
    __shared__ int curL[NBUCKETS];
    int t = threadIdx.x;
    int e0 = blockIdx.x * EPB;
    int e1 = e0 + EPB; if (e1 > E) e1 = E;

    for (int i = t; i < NBUCKETS; i += 256) curL[i] = 0;
    __syncthreads();
    for (int i = e0 + t; i < e1; i += 256) atomicAdd(&curL[dst[i] >> BSHIFT], 1);
    __syncthreads();
    for (int i = t; i < NBUCKETS; i += 256) {
        int h = curL[i];
        curL[i] = h ? atomicAdd(&bcur[i], h) : 0;
    }
    __syncthreads();
    for (int i = e0 + t; i < e1; i += 256) {
        int d = dst[i], s = src[i];
        int b = d >> BSHIFT;
        int pos = atomicAdd(&curL[b], 1);
        if (pos < BCAP) ebuf[(size_t)b * BCAP + pos] = ((uint)(d & (BNODES - 1)) << 17) | (uint)s;
    }
}

// S2: per-bucket counting sort; emits ssrc + rs + cnt + dinv.
__global__ __launch_bounds__(256)
void bucket_sort_kernel(const uint* __restrict__ ebuf, const int* __restrict__ bcur,
                        int* __restrict__ ssrc, int* __restrict__ rs, int* __restrict__ cnt,
                        float* __restrict__ dinv, int n) {
    __shared__ uint eL[BCAP];          // 24 KB
    __shared__ int hist[BNODES], ps[BNODES];
    int b = blockIdx.x, t = threadIdx.x;
    int nb = bcur[b];
    if (nb > BCAP) nb = BCAP;
    for (int i = t; i < nb; i += 256) eL[i] = ebuf[(size_t)b * BCAP + i];
    hist[t] = 0;
    __syncthreads();
    for (int i = t; i < nb; i += 256) atomicAdd(&hist[eL[i] >> 17], 1);
    __syncthreads();
    ps[t] = hist[t];
    __syncthreads();
#pragma unroll
    for (int off = 1; off < BNODES; off <<= 1) {
        int v = (t >= off) ? ps[t - off] : 0;
        __syncthreads();
        ps[t] += v;
        __syncthreads();
    }
    int excl = ps[t] - hist[t];
    int node = b * BNODES + t;
    if (node < n) {
        rs[node] = b * BCAP + excl;
        cnt[node] = hist[t];
        dinv[node] = 1.0f / sqrtf((float)hist[t] + 1.0f);
    }
    __syncthreads();
    ps[t] = excl;                      // reuse as running cursor
    __syncthreads();
    for (int i = t; i < nb; i += 256) {
        uint e = eL[i];
        int d = e >> 17;
        int p = atomicAdd(&ps[d], 1);
        ssrc[(size_t)b * BCAP + p] = (int)(e & 0x1FFFF);
    }
}

// ---------------- weight prep: fragment-ordered bf16 ----------------
// mfma_f32_16x16x32_bf16 B-frag: lane holds B[k=(lane>>4)*8+j][n=lane&15].
__global__ __launch_bounds__(256)
void wprep_kernel(const float* __restrict__ W1, const float* __restrict__ W2,
                  short8* __restrict__ W1f, short8* __restrict__ W2f) {
    int b = blockIdx.x;
    if (b < 16) {
        int f = b * 256 + threadIdx.x;
        int k0 = f >> 9, nt = (f >> 6) & 7, ln = f & 63;
        int kbase = k0 * 32 + (ln >> 4) * 8;
        int n = nt * 16 + (ln & 15);
        short8 fr;
#pragma unroll
        for (int j = 0; j < 8; ++j) fr[j] = (short)bf16_rne(W1[(kbase + j) * F_MID + n]);
        W1f[f] = fr;
    } else {
        int f = (b - 16) * 256 + threadIdx.x;
        int k0 = f >> 8, nt = (f >> 6) & 3, ln = f & 63;
        int kbase = k0 * 32 + (ln >> 4) * 8;
        int n = nt * 16 + (ln & 15);
        short8 fr;
#pragma unroll
        for (int j = 0; j < 8; ++j) fr[j] = (short)bf16_rne(W2[(kbase + j) * F_OUT + n]);
        W2f[f] = fr;
    }
}

// ---------------- MFMA GEMMs ----------------
// A: lane holds A[m=lane&15][k=(lane>>4)*8+j]; C/D: col=lane&15, row=(lane>>4)*4+reg.

// h1s[M,128](bf16) = dinv[m] * (x[M,256](fp32) @ W1bf16)
// 8 waves x 16 rows = 128-row tile. A staged per 64-col K-chunk into LDS as
// bf16 in A-frag order (coalesced global loads, convert during staging,
// XOR-swizzled slots). Double-buffered; 1 barrier/chunk.
__global__ __launch_bounds__(512, 2)
void gemm1_kernel(const float* __restrict__ A, const short8* __restrict__ Wf,
                  const float* __restrict__ dinv, ushort* __restrict__ C,
                  int M) {
    __shared__ short8 BsF[4096];          // 64 KB: W1 fragments
    __shared__ ushort Abuf[2][128 * 64];  // 2 x 16 KB: bf16 A chunks
    int tid = threadIdx.x;
    int lane = tid & 63, w = tid >> 6;    // w in 0..7
    int m0 = blockIdx.x * 128;

    // per-thread staging slots: o = tid*2 + {0,1} in [0,1024)
    //   row = o>>3, cl = o&7 (dest slot), cg = cl ^ (row&7) (source chunk)
    //   src = A[(m0+row)*256 + kc*64 + cg*8 .. +8)   (8 floats = 32 B)
    //   dst = Abuf[b][o*8 .. +8)                      (8 bf16  = 16 B)
    int o0 = tid * 2;
    int srow = o0 >> 3;                   // both slots share the row
    int gr = m0 + srow; if (gr >= M) gr = m0;   // clamp (garbage rows unused)
    int cl0 = o0 & 7, cl1 = cl0 + 1;
    int cg0 = cl0 ^ (srow & 7), cg1 = cl1 ^ (srow & 7);
    const float* arow = &A[(size_t)gr * F_IN];

    float4 rv[2][2];
    // issue chunk 0 loads first (long-latency), then W staging overlaps
    rv[0][0] = ((const float4*)(arow + cg0 * 8))[0];
    rv[0][1] = ((const float4*)(arow + cg0 * 8))[1];
    rv[1][0] = ((const float4*)(arow + cg1 * 8))[0];
    rv[1][1] = ((const float4*)(arow + cg1 * 8))[1];

    for (int f = tid; f < 4096; f += 512) BsF[f] = Wf[f];

    // convert + write chunk 0
    {
        short8 pk;
        pk[0] = (short)bf16_rne(rv[0][0].x); pk[1] = (short)bf16_rne(rv[0][0].y);
        pk[2] = (short)bf16_rne(rv[0][0].z); pk[3] = (short)bf16_rne(rv[0][0].w);
        pk[4] = (short)bf16_rne(rv[0][1].x); pk[5] = (short)bf16_rne(rv[0][1].y);
        pk[6] = (short)bf16_rne(rv[0][1].z); pk[7] = (short)bf16_rne(rv[0][1].w);
        *(short8*)&Abuf[0][o0 * 8] = pk;
        pk[0] = (short)bf16_rne(rv[1][0].x); pk[1] = (short)bf16_rne(rv[1][0].y);
        pk[2] = (short)bf16_rne(rv[1][0].z); pk[3] = (short)bf16_rne(rv[1][0].w);
        pk[4] = (short)bf16_rne(rv[1][1].x); pk[5] = (short)bf16_rne(rv[1][1].y);
        pk[6] = (short)bf16_rne(rv[1][1].z); pk[7] = (short)bf16_rne(rv[1][1].w);
        *(short8*)&Abuf[0][(o0 + 1) * 8] = pk;
    }
    __syncthreads();

    f32x4 acc[8];
#pragma unroll
    for (int nt = 0; nt < 8; ++nt) acc[nt] = (f32x4){0.f, 0.f, 0.f, 0.f};

    int arow16 = w * 16 + (lane & 15);    // this lane's A-frag row in tile
    int asw = arow16 & 7;
    int abase = arow16 * 8;               // slot base for that row

#pragma unroll
    for (int kc = 0; kc < 4; ++kc) {
        int b = kc & 1;
        if (kc < 3) {
            // issue next-chunk loads BEFORE compute; fence stops sinking
            const float* s0 = arow + (kc + 1) * 64 + cg0 * 8;
            const float* s1 = arow + (kc + 1) * 64 + cg1 * 8;
            rv[0][0] = ((const float4*)s0)[0];
            rv[0][1] = ((const float4*)s0)[1];
            rv[1][0] = ((const float4*)s1)[0];
            rv[1][1] = ((const float4*)s1)[1];
            asm volatile("" ::: "memory");
        }
#pragma unroll
        for (int kk = 0; kk < 2; ++kk) {
            int k0 = kc * 2 + kk;
            int c = kk * 4 + (lane >> 4);
            short8 af = *(const short8*)&Abuf[b][(abase + (c ^ asw)) * 8];
#pragma unroll
            for (int nt = 0; nt < 8; ++nt) {
                short8 bfr = BsF[(k0 * 8 + nt) * 64 + lane];
                acc[nt] = __builtin_amdgcn_mfma_f32_16x16x32_bf16(af, bfr, acc[nt], 0, 0, 0);
            }
        }
        if (kc < 3) {
            short8 pk;
            pk[0] = (short)bf16_rne(rv[0][0].x); pk[1] = (short)bf16_rne(rv[0][0].y);
            pk[2] = (short)bf16_rne(rv[0][0].z); pk[3] = (short)bf16_rne(rv[0][0].w);
            pk[4] = (short)bf16_rne(rv[0][1].x); pk[5] = (short)bf16_rne(rv[0][1].y);
            pk[6] = (short)bf16_rne(rv[0][1].z); pk[7] = (short)bf16_rne(rv[0][1].w);
            *(short8*)&Abuf[b ^ 1][o0 * 8] = pk;
            pk[0] = (short)bf16_rne(rv[1][0].x); pk[1] = (short)bf16_rne(rv[1][0].y);
            pk[2] = (short)bf16_rne(rv[1][0].z); pk[3] = (short)bf16_rne(rv[1][0].w);
            pk[4] = (short)bf16_rne(rv[1][1].x); pk[5] = (short)bf16_rne(rv[1][1].y);
            pk[6] = (short)bf16_rne(rv[1][1].z); pk[7] = (short)bf16_rne(rv[1][1].w);
            *(short8*)&Abuf[b ^ 1][(o0 + 1) * 8] = pk;
        }
        __syncthreads();
    }

#pragma unroll
    for (int i = 0; i < 4; ++i) {
        int r = blockIdx.x * 128 + w * 16 + (lane >> 4) * 4 + i;
        if (r < M) {
            float dv = dinv[r];
#pragma unroll
            for (int nt = 0; nt < 8; ++nt)
                C[(size_t)r * F_MID + nt * 16 + (lane & 15)] = bf16_rne(dv * acc[nt][i]);
        }
    }
}

// h2s[M,64](bf16) = dinv[m] * (h1a[M,128](bf16) @ W2bf16)
__global__ __launch_bounds__(512, 4)
void gemm2_kernel(const ushort* __restrict__ A, const short8* __restrict__ Wf,
                  const float* __restrict__ dinv, ushort* __restrict__ C,
                  int M) {
    __shared__ short8 BsF[1024];   // 16 KB
    int tid = threadIdx.x;
    int lane = tid & 63, w = tid >> 6;
    for (int f = tid; f < 1024; f += 512) BsF[f] = Wf[f];
    __syncthreads();

    int m0 = blockIdx.x * 128 + w * 16;
    int m = m0 + (lane & 15);
    bool mOk = (m < M);

    f32x4 acc[4];
#pragma unroll
    for (int nt = 0; nt < 4; ++nt) acc[nt] = (f32x4){0.f, 0.f, 0.f, 0.f};

    short8 afr[4];
#pragma unroll
    for (int k0 = 0; k0 < 4; ++k0) {
        short8 af = (short8){0, 0, 0, 0, 0, 0, 0, 0};
        if (mOk) af = *(const short8*)&A[(size_t)m * F_MID + k0 * 32 + (lane >> 4) * 8];
        afr[k0] = af;
    }
#pragma unroll
    for (int k0 = 0; k0 < 4; ++k0)
#pragma unroll
        for (int nt = 0; nt < 4; ++nt) {
            short8 bfr = BsF[(k0 * 4 + nt) * 64 + lane];
            acc[nt] = __builtin_amdgcn_mfma_f32_16x16x32_bf16(afr[k0], bfr, acc[nt], 0, 0, 0);
        }
#pragma unroll
    for (int i = 0; i < 4; ++i) {
        int r = m0 + (lane >> 4) * 4 + i;
        if (r < M) {
            float dv = dinv[r];
#pragma unroll
            for (int nt = 0; nt < 4; ++nt)
                C[(size_t)r * F_OUT + nt * 16 + (lane & 15)] = bf16_rne(dv * acc[nt][i]);
        }
    }
}

// ---------------- aggregation ----------------
// agg1: rows pre-scaled by dinv[src]. One wave/node; quarter q handles edges
// base+4j+q, j=0..3 (x4 unroll -> 16 gathers in flight); 16 lanes x uint4
// (16B) cover the 256-B row; butterfly fold at end.
__global__ __launch_bounds__(256)
void agg1_kernel(const uint4* __restrict__ h, const int* __restrict__ rs,
                 const int* __restrict__ cnt, const int* __restrict__ ssrc,
                 const float* __restrict__ dinv, const float* __restrict__ bias,
                 uint4* __restrict__ outp, int n) {
    int w = threadIdx.x >> 6, lane = threadIdx.x & 63;
    int node = blockIdx.x * 4 + w;
    if (node >= n) return;
    int q = lane >> 4, c16 = lane & 15;
    int start = rs[node], c = cnt[node];
    float dn = dinv[node];
    float a[8];
#pragma unroll
    for (int i = 0; i < 8; ++i) a[i] = 0.f;

    for (int base = 0; base < c; base += 16) {
        bool p[4];
        int s[4];
        uint4 r[4];
#pragma unroll
        for (int j = 0; j < 4; ++j) {
            int e = base + j * 4 + q;
            p[j] = e < c;
            if (p[j]) s[j] = ssrc[start + e];
        }
#pragma unroll
        for (int j = 0; j < 4; ++j)
            if (p[j]) r[j] = h[(size_t)s[j] * 16 + c16];
#pragma unroll
        for (int j = 0; j < 4; ++j) {
            if (p[j]) {
                a[0] += lo16(r[j].x); a[1] += hi16(r[j].x);
                a[2] += lo16(r[j].y); a[3] += hi16(r[j].y);
                a[4] += lo16(r[j].z); a[5] += hi16(r[j].z);
                a[6] += lo16(r[j].w); a[7] += hi16(r[j].w);
            }
        }
    }
#pragma unroll
    for (int i = 0; i < 8; ++i) {
        a[i] += __shfl_xor(a[i], 16);
        a[i] += __shfl_xor(a[i], 32);
    }
    uint4 sr = h[(size_t)node * 16 + c16];
    const float4* b4 = (const float4*)bias;
    float4 b0 = b4[c16 * 2], b1 = b4[c16 * 2 + 1];
    float o0 = fmaxf(fmaf(dn, a[0] + lo16(sr.x), b0.x), 0.f);
    float o1 = fmaxf(fmaf(dn, a[1] + hi16(sr.x), b0.y), 0.f);
    float o2 = fmaxf(fmaf(dn, a[2] + lo16(sr.y), b0.z), 0.f);
    float o3 = fmaxf(fmaf(dn, a[3] + hi16(sr.y), b0.w), 0.f);
    float o4 = fmaxf(fmaf(dn, a[4] + lo16(sr.z), b1.x), 0.f);
    float o5 = fmaxf(fmaf(dn, a[5] + hi16(sr.z), b1.y), 0.f);
    float o6 = fmaxf(fmaf(dn, a[6] + lo16(sr.w), b1.z), 0.f);
    float o7 = fmaxf(fmaf(dn, a[7] + hi16(sr.w), b1.w), 0.f);
    if (q == 0) {
        uint4 ov;
        ov.x = pack_bf2(o0, o1);
        ov.y = pack_bf2(o2, o3);
        ov.z = pack_bf2(o4, o5);
        ov.w = pack_bf2(o6, o7);
        outp[(size_t)node * 16 + c16] = ov;
    }
}

// agg2: 64-col bf16 rows (128 B), 16 lanes x uint2; x4-unrolled gather;
// fused bias + log_softmax.
__global__ __launch_bounds__(256)
void agg2_kernel(const uint2* __restrict__ h, const int* __restrict__ rs,
                 const int* __restrict__ cnt, const int* __restrict__ ssrc,
                 const float* __restrict__ dinv, const float* __restrict__ bias,
                 float4* __restrict__ out4, int n) {
    int w = threadIdx.x >> 6, lane = threadIdx.x & 63;
    int node = blockIdx.x * 4 + w;
    if (node >= n) return;
    int q = lane >> 4, c16 = lane & 15;
    int start = rs[node], c = cnt[node];
    float dn = dinv[node];
    float a[4];
#pragma unroll
    for (int i = 0; i < 4; ++i) a[i] = 0.f;

    for (int base = 0; base < c; base += 16) {
        bool p[4];
        int s[4];
        uint2 r[4];
#pragma unroll
        for (int j = 0; j < 4; ++j) {
            int e = base + j * 4 + q;
            p[j] = e < c;
            if (p[j]) s[j] = ssrc[start + e];
        }
#pragma unroll
        for (int j = 0; j < 4; ++j)
            if (p[j]) r[j] = h[(size_t)s[j] * 16 + c16];
#pragma unroll
        for (int j = 0; j < 4; ++j) {
            if (p[j]) {
                a[0] += lo16(r[j].x); a[1] += hi16(r[j].x);
                a[2] += lo16(r[j].y); a[3] += hi16(r[j].y);
            }
        }
    }
#pragma unroll
    for (int i = 0; i < 4; ++i) {
        a[i] += __shfl_xor(a[i], 16);
        a[i] += __shfl_xor(a[i], 32);
    }
    uint2 sr = h[(size_t)node * 16 + c16];
    float4 bv = ((const float4*)bias)[c16];
    float v0 = fmaf(dn, a[0] + lo16(sr.x), bv.x);
    float v1 = fmaf(dn, a[1] + hi16(sr.x), bv.y);
    float v2 = fmaf(dn, a[2] + lo16(sr.y), bv.z);
    float v3 = fmaf(dn, a[3] + hi16(sr.y), bv.w);
    float m = fmaxf(fmaxf(v0, v1), fmaxf(v2, v3));
#pragma unroll
    for (int off = 1; off < 16; off <<= 1) m = fmaxf(m, __shfl_xor(m, off));
    float ssum = expf(v0 - m) + expf(v1 - m) + expf(v2 - m) + expf(v3 - m);
#pragma unroll
    for (int off = 1; off < 16; off <<= 1) ssum += __shfl_xor(ssum, off);
    float lg = m + logf(ssum);
    if (q == 0) out4[(size_t)node * 16 + c16] = make_float4(v0 - lg, v1 - lg, v2 - lg, v3 - lg);
}

// ---------------- launch ----------------

extern "C" void kernel_launch(void* const* d_in, const int* in_sizes, int n_in,
                              void* d_out, int out_size, void* d_ws, size_t ws_size,
                              hipStream_t stream) {
    const float* x  = (const float*)d_in[0];
    const int*   ei = (const int*)d_in[1];
    const float* W1 = (const float*)d_in[2];
    const float* b1 = (const float*)d_in[3];
    const float* W2 = (const float*)d_in[4];
    const float* b2 = (const float*)d_in[5];
    float* out = (float*)d_out;

    const int N = N_NODES;
    const int E = in_sizes[1] / 2;
    const int* src = ei;
    const int* dst = ei + E;

    char* ws = (char*)d_ws;
    size_t off = 0;
    auto alloc = [&](size_t bytes) {
        char* p = ws + off;
        off = (off + bytes + 255) & ~(size_t)255;
        return p;
    };
    int*    bcur   = (int*)alloc(NBUCKETS * 4);
    int*    rs     = (int*)alloc(N * 4);
    int*    cnt    = (int*)alloc(N * 4);
    float*  dinv   = (float*)alloc(N * 4);
    short8* W1f    = (short8*)alloc(4096 * 16);
    short8* W2f    = (short8*)alloc(1024 * 16);
    uint*   ebuf   = (uint*)alloc((size_t)NBUCKETS * BCAP * 4);   // 9.6 MB
    int*    ssrc   = (int*)alloc((size_t)NBUCKETS * BCAP * 4);    // 9.6 MB
    uint*   h1     = (uint*)alloc((size_t)N * 64 * 4);            // 128 bf16/row
    uint*   h1a    = (uint*)alloc((size_t)N * 64 * 4);
    ushort* h2     = (ushort*)h1;                                 // h1 dead after agg1

    const int nScatBlocks = (E + EPB - 1) / EPB;         // 391
    const int nAggBlocks  = (N + 3) / 4;
    const int nTiles      = (N + 127) / 128;             // 782

    hipMemsetAsync(bcur, 0, NBUCKETS * 4, stream);
    wprep_kernel<<<20, 256, 0, stream>>>(W1, W2, W1f, W2f);

    bucket_scatter_kernel<<<nScatBlocks, 256, 0, stream>>>(src, dst, bcur, ebuf, E);
    bucket_sort_kernel<<<NBUCKETS, 256, 0, stream>>>(ebuf, bcur, ssrc, rs, cnt, dinv, N);

    gemm1_kernel<<<nTiles, 512, 0, stream>>>(x, W1f, dinv, (ushort*)h1, N);
    agg1_kernel<<<nAggBlocks, 256, 0, stream>>>((const uint4*)h1, rs, cnt, ssrc, dinv, b1,
                                                (uint4*)h1a, N);
    gemm2_kernel<<<nTiles, 512, 0, stream>>>((const ushort*)h1a, W2f, dinv, h2, N);
    agg2_kernel<<<nAggBlocks, 256, 0, stream>>>((const uint2*)h2, rs, cnt, ssrc, dinv, b2,
                                                (float4*)out, N);
}

// Round 8
// 367.752 us; speedup vs baseline: 1.2150x; 1.0174x over previous
//
#include <hip/hip_runtime.h>
#include <hip/hip_bf16.h>

// GCN 2-layer: out = log_softmax(GCN2(relu(GCN1(x))))
// Round 15: resubmit of R14 (bench infra failed twice; no data). Fuse
// gemm2 into agg1. R13 established agg1's gather is at its structural
// floor (192 MB L2-miss vs 205 MB theoretical: 16 uses/row spread over
// 8 XCDs = 2 uses per private L2), so cut PIPELINE traffic: the
// aggregated h1a row is node-local input to gemm2's matvec ->
// block = 16 nodes (4 waves x 4 nodes serial), stage relu'd rows in LDS
// (stride-136 pad = 2-way banks), each wave does one 16-col tile of
// h2 = dinv*(h1a @ W2) with 4 MFMAs. Saves h1a write+read (51 MB round
// trip) and the whole gemm2 dispatch. Numerics bit-identical to the
// unfused path. gemm1 (R13 LDS-staged, worked), agg2, sort frozen.

#define N_NODES 100000
#define F_IN 256
#define F_MID 128
#define F_OUT 64

#define BSHIFT 8                      // 256 nodes per bucket
#define BNODES 256
#define NBUCKETS ((N_NODES + BNODES - 1) / BNODES)   // 391
#define BCAP 6144                     // mean 4096, sigma ~64 -> +32 sigma
#define EPB 4096                      // edges per scatter block

typedef __attribute__((ext_vector_type(8))) short short8;
typedef __attribute__((ext_vector_type(4))) float f32x4;

__device__ inline ushort bf16_rne(float f) {
    uint u = __float_as_uint(f);
    u += 0x7FFF + ((u >> 16) & 1);
    return (ushort)(u >> 16);
}
__device__ inline float lo16(uint r) { return __uint_as_float(r << 16); }
__device__ inline float hi16(uint r) { return __uint_as_float(r & 0xffff0000u); }
__device__ inline uint pack_bf2(float a, float b) {
    return (uint)bf16_rne(a) | ((uint)bf16_rne(b) << 16);
}

// ---------------- two-level bucket sort ----------------

// S1: block-binned scatter. packed = (dst&255)<<17 | src  (25 bits)
__global__ __launch_bounds__(256)
void bucket_scatter_kernel(const int* __restrict__ src, const int* __restrict__ dst,
                           int* __restrict__ bcur, uint* __restrict__ ebuf, int E) {
    __shared__ int curL[NBUCKETS];
    int t = threadIdx.x;
    int e0 = blockIdx.x * EPB;
    int e1 = e0 + EPB; if (e1 > E) e1 = E;

    for (int i = t; i < NBUCKETS; i += 256) curL[i] = 0;
    __syncthreads();
    for (int i = e0 + t; i < e1; i += 256) atomicAdd(&curL[dst[i] >> BSHIFT], 1);
    __syncthreads();
    for (int i = t; i < NBUCKETS; i += 256) {
        int h = curL[i];
        curL[i] = h ? atomicAdd(&bcur[i], h) : 0;
    }
    __syncthreads();
    for (int i = e0 + t; i < e1; i += 256) {
        int d = dst[i], s = src[i];
        int b = d >> BSHIFT;
        int pos = atomicAdd(&curL[b], 1);
        if (pos < BCAP) ebuf[(size_t)b * BCAP + pos] = ((uint)(d & (BNODES - 1)) << 17) | (uint)s;
    }
}

// S2: per-bucket counting sort; emits ssrc + rs + cnt + dinv.
__global__ __launch_bounds__(256)
void bucket_sort_kernel(const uint* __restrict__ ebuf, const int* __restrict__ bcur,
                        int* __restrict__ ssrc, int* __restrict__ rs, int* __restrict__ cnt,
                        float* __restrict__ dinv, int n) {
    __shared__ uint eL[BCAP];          // 24 KB
    __shared__ int hist[BNODES], ps[BNODES];
    int b = blockIdx.x, t = threadIdx.x;
    int nb = bcur[b];
    if (nb > BCAP) nb = BCAP;
    for (int i = t; i < nb; i += 256) eL[i] = ebuf[(size_t)b * BCAP + i];
    hist[t] = 0;
    __syncthreads();
    for (int i = t; i < nb; i += 256) atomicAdd(&hist[eL[i] >> 17], 1);
    __syncthreads();
    ps[t] = hist[t];
    __syncthreads();
#pragma unroll
    for (int off = 1; off < BNODES; off <<= 1) {
        int v = (t >= off) ? ps[t - off] : 0;
        __syncthreads();
        ps[t] += v;
        __syncthreads();
    }
    int excl = ps[t] - hist[t];
    int node = b * BNODES + t;
    if (node < n) {
        rs[node] = b * BCAP + excl;
        cnt[node] = hist[t];
        dinv[node] = 1.0f / sqrtf((float)hist[t] + 1.0f);
    }
    __syncthreads();
    ps[t] = excl;                      // reuse as running cursor
    __syncthreads();
    for (int i = t; i < nb; i += 256) {
        uint e = eL[i];
        int d = e >> 17;
        int p = atomicAdd(&ps[d], 1);
        ssrc[(size_t)b * BCAP + p] = (int)(e & 0x1FFFF);
    }
}

// ---------------- weight prep: fragment-ordered bf16 ----------------
// mfma_f32_16x16x32_bf16 B-frag: lane holds B[k=(lane>>4)*8+j][n=lane&15].
__global__ __launch_bounds__(256)
void wprep_kernel(const float* __restrict__ W1, const float* __restrict__ W2,
                  short8* __restrict__ W1f, short8* __restrict__ W2f) {
    int b = blockIdx.x;
    if (b < 16) {
        int f = b * 256 + threadIdx.x;
        int k0 = f >> 9, nt = (f >> 6) & 7, ln = f & 63;
        int kbase = k0 * 32 + (ln >> 4) * 8;
        int n = nt * 16 + (ln & 15);
        short8 fr;
#pragma unroll
        for (int j = 0; j < 8; ++j) fr[j] = (short)bf16_rne(W1[(kbase + j) * F_MID + n]);
        W1f[f] = fr;
    } else {
        int f = (b - 16) * 256 + threadIdx.x;
        int k0 = f >> 8, nt = (f >> 6) & 3, ln = f & 63;
        int kbase = k0 * 32 + (ln >> 4) * 8;
        int n = nt * 16 + (ln & 15);
        short8 fr;
#pragma unroll
        for (int j = 0; j < 8; ++j) fr[j] = (short)bf16_rne(W2[(kbase + j) * F_OUT + n]);
        W2f[f] = fr;
    }
}

// ---------------- MFMA GEMM 1 ----------------
// A: lane holds A[m=lane&15][k=(lane>>4)*8+j]; C/D: col=lane&15, row=(lane>>4)*4+reg.

// h1s[M,128](bf16) = dinv[m] * (x[M,256](fp32) @ W1bf16)
// 8 waves x 16 rows = 128-row tile. A staged per 64-col K-chunk into LDS as
// bf16 in A-frag order (coalesced global loads, convert during staging,
// XOR-swizzled slots). Double-buffered; 1 barrier/chunk.
__global__ __launch_bounds__(512, 2)
void gemm1_kernel(const float* __restrict__ A, const short8* __restrict__ Wf,
                  const float* __restrict__ dinv, ushort* __restrict__ C,
                  int M) {
    __shared__ short8 BsF[4096];          // 64 KB: W1 fragments
    __shared__ ushort Abuf[2][128 * 64];  // 2 x 16 KB: bf16 A chunks
    int tid = threadIdx.x;
    int lane = tid & 63, w = tid >> 6;    // w in 0..7
    int m0 = blockIdx.x * 128;

    int o0 = tid * 2;
    int srow = o0 >> 3;                   // both slots share the row
    int gr = m0 + srow; if (gr >= M) gr = m0;   // clamp (garbage rows unused)
    int cl0 = o0 & 7, cl1 = cl0 + 1;
    int cg0 = cl0 ^ (srow & 7), cg1 = cl1 ^ (srow & 7);
    const float* arow = &A[(size_t)gr * F_IN];

    float4 rv[2][2];
    rv[0][0] = ((const float4*)(arow + cg0 * 8))[0];
    rv[0][1] = ((const float4*)(arow + cg0 * 8))[1];
    rv[1][0] = ((const float4*)(arow + cg1 * 8))[0];
    rv[1][1] = ((const float4*)(arow + cg1 * 8))[1];

    for (int f = tid; f < 4096; f += 512) BsF[f] = Wf[f];

    {
        short8 pk;
        pk[0] = (short)bf16_rne(rv[0][0].x); pk[1] = (short)bf16_rne(rv[0][0].y);
        pk[2] = (short)bf16_rne(rv[0][0].z); pk[3] = (short)bf16_rne(rv[0][0].w);
        pk[4] = (short)bf16_rne(rv[0][1].x); pk[5] = (short)bf16_rne(rv[0][1].y);
        pk[6] = (short)bf16_rne(rv[0][1].z); pk[7] = (short)bf16_rne(rv[0][1].w);
        *(short8*)&Abuf[0][o0 * 8] = pk;
        pk[0] = (short)bf16_rne(rv[1][0].x); pk[1] = (short)bf16_rne(rv[1][0].y);
        pk[2] = (short)bf16_rne(rv[1][0].z); pk[3] = (short)bf16_rne(rv[1][0].w);
        pk[4] = (short)bf16_rne(rv[1][1].x); pk[5] = (short)bf16_rne(rv[1][1].y);
        pk[6] = (short)bf16_rne(rv[1][1].z); pk[7] = (short)bf16_rne(rv[1][1].w);
        *(short8*)&Abuf[0][(o0 + 1) * 8] = pk;
    }
    __syncthreads();

    f32x4 acc[8];
#pragma unroll
    for (int nt = 0; nt < 8; ++nt) acc[nt] = (f32x4){0.f, 0.f, 0.f, 0.f};

    int arow16 = w * 16 + (lane & 15);    // this lane's A-frag row in tile
    int asw = arow16 & 7;
    int abase = arow16 * 8;               // slot base for that row

#pragma unroll
    for (int kc = 0; kc < 4; ++kc) {
        int b = kc & 1;
        if (kc < 3) {
            const float* s0 = arow + (kc + 1) * 64 + cg0 * 8;
            const float* s1 = arow + (kc + 1) * 64 + cg1 * 8;
            rv[0][0] = ((const float4*)s0)[0];
            rv[0][1] = ((const float4*)s0)[1];
            rv[1][0] = ((const float4*)s1)[0];
            rv[1][1] = ((const float4*)s1)[1];
            asm volatile("" ::: "memory");
        }
#pragma unroll
        for (int kk = 0; kk < 2; ++kk) {
            int k0 = kc * 2 + kk;
            int c = kk * 4 + (lane >> 4);
            short8 af = *(const short8*)&Abuf[b][(abase + (c ^ asw)) * 8];
#pragma unroll
            for (int nt = 0; nt < 8; ++nt) {
                short8 bfr = BsF[(k0 * 8 + nt) * 64 + lane];
                acc[nt] = __builtin_amdgcn_mfma_f32_16x16x32_bf16(af, bfr, acc[nt], 0, 0, 0);
            }
        }
        if (kc < 3) {
            short8 pk;
            pk[0] = (short)bf16_rne(rv[0][0].x); pk[1] = (short)bf16_rne(rv[0][0].y);
            pk[2] = (short)bf16_rne(rv[0][0].z); pk[3] = (short)bf16_rne(rv[0][0].w);
            pk[4] = (short)bf16_rne(rv[0][1].x); pk[5] = (short)bf16_rne(rv[0][1].y);
            pk[6] = (short)bf16_rne(rv[0][1].z); pk[7] = (short)bf16_rne(rv[0][1].w);
            *(short8*)&Abuf[b ^ 1][o0 * 8] = pk;
            pk[0] = (short)bf16_rne(rv[1][0].x); pk[1] = (short)bf16_rne(rv[1][0].y);
            pk[2] = (short)bf16_rne(rv[1][0].z); pk[3] = (short)bf16_rne(rv[1][0].w);
            pk[4] = (short)bf16_rne(rv[1][1].x); pk[5] = (short)bf16_rne(rv[1][1].y);
            pk[6] = (short)bf16_rne(rv[1][1].z); pk[7] = (short)bf16_rne(rv[1][1].w);
            *(short8*)&Abuf[b ^ 1][(o0 + 1) * 8] = pk;
        }
        __syncthreads();
    }

#pragma unroll
    for (int i = 0; i < 4; ++i) {
        int r = blockIdx.x * 128 + w * 16 + (lane >> 4) * 4 + i;
        if (r < M) {
            float dv = dinv[r];
#pragma unroll
            for (int nt = 0; nt < 8; ++nt)
                C[(size_t)r * F_MID + nt * 16 + (lane & 15)] = bf16_rne(dv * acc[nt][i]);
        }
    }
}

// ---------------- fused aggregation-1 + gemm2 ----------------
// Block = 256 threads = 4 waves, 16 nodes. Phase 1: wave w serially
// aggregates nodes base+w*4+i (quarter q handles edges base+4j+q, x4
// unroll), applies dinv/b1/relu, stages the 128-col bf16 row into LDS
// (stride 136 shorts -> 2-way banks). Phase 2: wave w computes h2 col-tile
// nt=w for all 16 rows via 4 MFMAs: h2 = dinv * (rows @ W2).
__global__ __launch_bounds__(256)
void agg1f_kernel(const uint4* __restrict__ h, const int* __restrict__ rs,
                  const int* __restrict__ cnt, const int* __restrict__ ssrc,
                  const float* __restrict__ dinv, const float* __restrict__ bias,
                  const short8* __restrict__ W2f, ushort* __restrict__ h2, int n) {
    __shared__ __align__(16) ushort rowsL[16][136];   // 16 rows x 128 bf16 + pad
    int w = threadIdx.x >> 6, lane = threadIdx.x & 63;
    int q = lane >> 4, c16 = lane & 15;
    int nbase = blockIdx.x * 16;
    const float4* b4 = (const float4*)bias;
    float4 b0 = b4[c16 * 2], b1v = b4[c16 * 2 + 1];

#pragma unroll
    for (int i = 0; i < 4; ++i) {
        int node = nbase + w * 4 + i;
        bool nOk = (node < n);
        int start = nOk ? rs[node] : 0;
        int c = nOk ? cnt[node] : 0;
        float dn = nOk ? dinv[node] : 0.f;
        float a[8];
#pragma unroll
        for (int k = 0; k < 8; ++k) a[k] = 0.f;

        for (int base = 0; base < c; base += 16) {
            bool p[4];
            int s[4];
            uint4 r[4];
#pragma unroll
            for (int j = 0; j < 4; ++j) {
                int e = base + j * 4 + q;
                p[j] = e < c;
                if (p[j]) s[j] = ssrc[start + e];
            }
#pragma unroll
            for (int j = 0; j < 4; ++j)
                if (p[j]) r[j] = h[(size_t)s[j] * 16 + c16];
#pragma unroll
            for (int j = 0; j < 4; ++j) {
                if (p[j]) {
                    a[0] += lo16(r[j].x); a[1] += hi16(r[j].x);
                    a[2] += lo16(r[j].y); a[3] += hi16(r[j].y);
                    a[4] += lo16(r[j].z); a[5] += hi16(r[j].z);
                    a[6] += lo16(r[j].w); a[7] += hi16(r[j].w);
                }
            }
        }
#pragma unroll
        for (int k = 0; k < 8; ++k) {
            a[k] += __shfl_xor(a[k], 16);
            a[k] += __shfl_xor(a[k], 32);
        }
        if (q == 0) {
            short8 pk;
            if (nOk) {
                uint4 sr = h[(size_t)node * 16 + c16];
                float o0 = fmaxf(fmaf(dn, a[0] + lo16(sr.x), b0.x), 0.f);
                float o1 = fmaxf(fmaf(dn, a[1] + hi16(sr.x), b0.y), 0.f);
                float o2 = fmaxf(fmaf(dn, a[2] + lo16(sr.y), b0.z), 0.f);
                float o3 = fmaxf(fmaf(dn, a[3] + hi16(sr.y), b0.w), 0.f);
                float o4 = fmaxf(fmaf(dn, a[4] + lo16(sr.z), b1v.x), 0.f);
                float o5 = fmaxf(fmaf(dn, a[5] + hi16(sr.z), b1v.y), 0.f);
                float o6 = fmaxf(fmaf(dn, a[6] + lo16(sr.w), b1v.z), 0.f);
                float o7 = fmaxf(fmaf(dn, a[7] + hi16(sr.w), b1v.w), 0.f);
                pk[0] = (short)bf16_rne(o0); pk[1] = (short)bf16_rne(o1);
                pk[2] = (short)bf16_rne(o2); pk[3] = (short)bf16_rne(o3);
                pk[4] = (short)bf16_rne(o4); pk[5] = (short)bf16_rne(o5);
                pk[6] = (short)bf16_rne(o6); pk[7] = (short)bf16_rne(o7);
            } else {
                pk = (short8){0, 0, 0, 0, 0, 0, 0, 0};
            }
            *(short8*)&rowsL[w * 4 + i][c16 * 8] = pk;
        }
    }
    __syncthreads();

    // phase 2: wave w -> col-tile nt=w. A: lane reads LDS row (lane&15),
    // k-slice k0*32+(lane>>4)*8; B: W2f[(k0*4+w)*64+lane] (L2-hot, 16 KB).
    f32x4 acc = (f32x4){0.f, 0.f, 0.f, 0.f};
    int ar = lane & 15;
#pragma unroll
    for (int k0 = 0; k0 < 4; ++k0) {
        short8 af = *(const short8*)&rowsL[ar][k0 * 32 + (lane >> 4) * 8];
        short8 bfr = W2f[(k0 * 4 + w) * 64 + lane];
        acc = __builtin_amdgcn_mfma_f32_16x16x32_bf16(af, bfr, acc, 0, 0, 0);
    }
#pragma unroll
    for (int i = 0; i < 4; ++i) {
        int r = (lane >> 4) * 4 + i;
        int node = nbase + r;
        if (node < n) {
            float dv = dinv[node];
            h2[(size_t)node * F_OUT + w * 16 + (lane & 15)] = bf16_rne(dv * acc[i]);
        }
    }
}

// agg2: 64-col bf16 rows (128 B), 16 lanes x uint2; x4-unrolled gather;
// fused bias + log_softmax.
__global__ __launch_bounds__(256)
void agg2_kernel(const uint2* __restrict__ h, const int* __restrict__ rs,
                 const int* __restrict__ cnt, const int* __restrict__ ssrc,
                 const float* __restrict__ dinv, const float* __restrict__ bias,
                 float4* __restrict__ out4, int n) {
    int w = threadIdx.x >> 6, lane = threadIdx.x & 63;
    int node = blockIdx.x * 4 + w;
    if (node >= n) return;
    int q = lane >> 4, c16 = lane & 15;
    int start = rs[node], c = cnt[node];
    float dn = dinv[node];
    float a[4];
#pragma unroll
    for (int i = 0; i < 4; ++i) a[i] = 0.f;

    for (int base = 0; base < c; base += 16) {
        bool p[4];
        int s[4];
        uint2 r[4];
#pragma unroll
        for (int j = 0; j < 4; ++j) {
            int e = base + j * 4 + q;
            p[j] = e < c;
            if (p[j]) s[j] = ssrc[start + e];
        }
#pragma unroll
        for (int j = 0; j < 4; ++j)
            if (p[j]) r[j] = h[(size_t)s[j] * 16 + c16];
#pragma unroll
        for (int j = 0; j < 4; ++j) {
            if (p[j]) {
                a[0] += lo16(r[j].x); a[1] += hi16(r[j].x);
                a[2] += lo16(r[j].y); a[3] += hi16(r[j].y);
            }
        }
    }
#pragma unroll
    for (int i = 0; i < 4; ++i) {
        a[i] += __shfl_xor(a[i], 16);
        a[i] += __shfl_xor(a[i], 32);
    }
    uint2 sr = h[(size_t)node * 16 + c16];
    float4 bv = ((const float4*)bias)[c16];
    float v0 = fmaf(dn, a[0] + lo16(sr.x), bv.x);
    float v1 = fmaf(dn, a[1] + hi16(sr.x), bv.y);
    float v2 = fmaf(dn, a[2] + lo16(sr.y), bv.z);
    float v3 = fmaf(dn, a[3] + hi16(sr.y), bv.w);
    float m = fmaxf(fmaxf(v0, v1), fmaxf(v2, v3));
#pragma unroll
    for (int off = 1; off < 16; off <<= 1) m = fmaxf(m, __shfl_xor(m, off));
    float ssum = expf(v0 - m) + expf(v1 - m) + expf(v2 - m) + expf(v3 - m);
#pragma unroll
    for (int off = 1; off < 16; off <<= 1) ssum += __shfl_xor(ssum, off);
    float lg = m + logf(ssum);
    if (q == 0) out4[(size_t)node * 16 + c16] = make_float4(v0 - lg, v1 - lg, v2 - lg, v3 - lg);
}

// ---------------- launch ----------------

extern "C" void kernel_launch(void* const* d_in, const int* in_sizes, int n_in,
                              void* d_out, int out_size, void* d_ws, size_t ws_size,
                              hipStream_t stream) {
    const float* x  = (const float*)d_in[0];
    const int*   ei = (const int*)d_in[1];
    const float* W1 = (const float*)d_in[2];
    const float* b1 = (const float*)d_in[3];
    const float* W2 = (const float*)d_in[4];
    const float* b2 = (const float*)d_in[5];
    float* out = (float*)d_out;

    const int N = N_NODES;
    const int E = in_sizes[1] / 2;
    const int* src = ei;
    const int* dst = ei + E;

    char* ws = (char*)d_ws;
    size_t off = 0;
    auto alloc = [&](size_t bytes) {
        char* p = ws + off;
        off = (off + bytes + 255) & ~(size_t)255;
        return p;
    };
    int*    bcur   = (int*)alloc(NBUCKETS * 4);
    int*    rs     = (int*)alloc(N * 4);
    int*    cnt    = (int*)alloc(N * 4);
    float*  dinv   = (float*)alloc(N * 4);
    short8* W1f    = (short8*)alloc(4096 * 16);
    short8* W2f    = (short8*)alloc(1024 * 16);
    uint*   ebuf   = (uint*)alloc((size_t)NBUCKETS * BCAP * 4);   // 9.6 MB
    int*    ssrc   = (int*)alloc((size_t)NBUCKETS * BCAP * 4);    // 9.6 MB
    uint*   h1     = (uint*)alloc((size_t)N * 64 * 4);            // 128 bf16/row
    ushort* h2     = (ushort*)alloc((size_t)N * 64 * 2);          // 64 bf16/row

    const int nScatBlocks = (E + EPB - 1) / EPB;         // 391
    const int nAgg1Blocks = (N + 15) / 16;               // 6250
    const int nAgg2Blocks = (N + 3) / 4;
    const int nTiles      = (N + 127) / 128;             // 782

    hipMemsetAsync(bcur, 0, NBUCKETS * 4, stream);
    wprep_kernel<<<20, 256, 0, stream>>>(W1, W2, W1f, W2f);

    bucket_scatter_kernel<<<nScatBlocks, 256, 0, stream>>>(src, dst, bcur, ebuf, E);
    bucket_sort_kernel<<<NBUCKETS, 256, 0, stream>>>(ebuf, bcur, ssrc, rs, cnt, dinv, N);

    gemm1_kernel<<<nTiles, 512, 0, stream>>>(x, W1f, dinv, (ushort*)h1, N);
    agg1f_kernel<<<nAgg1Blocks, 256, 0, stream>>>((const uint4*)h1, rs, cnt, ssrc, dinv, b1,
                                                  W2f, h2, N);
    agg2_kernel<<<nAgg2Blocks, 256, 0, stream>>>((const uint2*)h2, rs, cnt, ssrc, dinv, b2,
                                                 (float4*)out, N);
}